// Round 5
// baseline (77429.492 us; speedup 1.0000x reference)
//
#include <hip/hip_runtime.h>
#include <hip/hip_cooperative_groups.h>
#include <cstddef>

namespace cg = cooperative_groups;

// SafetyReflexSNN: 5-layer LIF SNN, B=128, T=512.
//
// ROUND 16: PERSISTENT COOPERATIVE KERNEL. Rounds 14/15 both landed at
// ~47 us/phase despite very different inner loops -> per-launch fixed cost
// (~20-25 us: dispatch + end-of-kernel drain + inter-XCD L2 flush) dominates
// 517 launches. This round moves the phase loop inside ONE cooperative
// kernel with grid.sync() between phases (agent-scope fences included by
// ROCm's grid sync -> cross-XCD producer/consumer is safe). Stage internals
// are byte-for-byte round-15 (absmax 0.0 proven). Fallback: round-15
// multi-launch path if cooperative launch is rejected.
//
// NUMERICS: per output element the op sequence is value-identical to
// round-11/14/15: ascending-k fmaf chain per panel; K=1024 combines panels
// with one __fadd_rn(low, high); layer-2 combine = one __fadd_rn(W2a_res,
// W2b_res); LIF = __fmul_rn / __fadd_rn / __fsub_rn; counts in ascending t.

#define NB 128
#define NT 512

// ---- workspace layout (floats) ----
enum : size_t {
  OFF_V0   = 0,                       // [128][1024]
  OFF_V1   = OFF_V0 + 131072,
  OFF_V2   = OFF_V1 + 131072,
  OFF_V3   = OFF_V2 + 131072,         // [128][512]
  OFF_VO   = OFF_V3 + 65536,          // [128][128]
  OFF_CNT  = OFF_VO + 16384,          // [128][128]
  OFF_C2A  = OFF_CNT + 16384,         // 2 x [128][1024] float
  OFF_BYTE = OFF_C2A + 262144,        // byte region starts here (float idx)
  WS_FLOATS = OFF_BYTE + 229376       // 983040 floats = 3.93 MB
};
#define BS0 0
#define BS1 262144
#define BS2 524288
#define BS3 786432

// ---- LDS staging helpers (transposed layouts) ----
__device__ __forceinline__ void wrA8(float (&A)[32][32], int ac, int ar, uint2 u) {
  A[ac + 0][ar] = (float)(u.x & 0xff);
  A[ac + 1][ar] = (float)((u.x >> 8) & 0xff);
  A[ac + 2][ar] = (float)((u.x >> 16) & 0xff);
  A[ac + 3][ar] = (float)(u.x >> 24);
  A[ac + 4][ar] = (float)(u.y & 0xff);
  A[ac + 5][ar] = (float)((u.y >> 8) & 0xff);
  A[ac + 6][ar] = (float)((u.y >> 16) & 0xff);
  A[ac + 7][ar] = (float)(u.y >> 24);
}
__device__ __forceinline__ void wrW16(float (&Wt)[32][68], int wk, int wr,
    const float4& w0, const float4& w1, const float4& w2, const float4& w3) {
  Wt[wk + 0][wr]      = w0.x; Wt[wk + 1][wr]      = w0.y;
  Wt[wk + 2][wr]      = w0.z; Wt[wk + 3][wr]      = w0.w;
  Wt[wk + 0][wr + 16] = w1.x; Wt[wk + 1][wr + 16] = w1.y;
  Wt[wk + 2][wr + 16] = w1.z; Wt[wk + 3][wr + 16] = w1.w;
  Wt[wk + 0][wr + 32] = w2.x; Wt[wk + 1][wr + 32] = w2.y;
  Wt[wk + 2][wr + 32] = w2.z; Wt[wk + 3][wr + 32] = w2.w;
  Wt[wk + 0][wr + 48] = w3.x; Wt[wk + 1][wr + 48] = w3.y;
  Wt[wk + 2][wr + 48] = w3.z; Wt[wk + 3][wr + 48] = w3.w;
}
__device__ __forceinline__ void wrA4f(float (&A)[32][32], int ac4, int ar, float4 f) {
  A[ac4 + 0][ar] = f.x; A[ac4 + 1][ar] = f.y;
  A[ac4 + 2][ar] = f.z; A[ac4 + 3][ar] = f.w;
}
__device__ __forceinline__ void wrA4b(float (&A)[32][32], int ac4, int ar, unsigned u) {
  A[ac4 + 0][ar] = (float)(u & 0xff);
  A[ac4 + 1][ar] = (float)((u >> 8) & 0xff);
  A[ac4 + 2][ar] = (float)((u >> 16) & 0xff);
  A[ac4 + 3][ar] = (float)(u >> 24);
}
__device__ __forceinline__ void wrW8(float (&Wt)[32][68], int wk2, int wr,
    const float4& w0, const float4& w1) {
  Wt[wk2 + 0][wr] = w0.x; Wt[wk2 + 1][wr] = w0.y;
  Wt[wk2 + 2][wr] = w0.z; Wt[wk2 + 3][wr] = w0.w;
  Wt[wk2 + 4][wr] = w1.x; Wt[wk2 + 5][wr] = w1.y;
  Wt[wk2 + 6][wr] = w1.z; Wt[wk2 + 7][wr] = w1.w;
}

// ---- split GEMM: K=1024, 256 thr, wave-group panel split at k=512.
// Tile 32 (b) x 64 (o). Per group: micro 4x4, NKT=16 k-tiles of 32.
__device__ __forceinline__ void gemm_split(
    const unsigned char* __restrict__ Abase, int Astride,
    const float* __restrict__ W,  // [o][1024]
    int bBase, int oBase,
    float (&As)[2][2][32][32], float (&Ws)[2][2][32][68],
    float (&pan)[4][4])
{
  const int tid = threadIdx.x;
  const int grp = tid >> 7, lt = tid & 127;
  const int ar = lt >> 2, ac = (lt & 3) << 3;
  const int wr = lt >> 3, wk = (lt & 7) << 2;
  const int tb4 = (lt >> 4) << 2;
  const int to4 = (lt & 15) << 2;
  const int kb = grp << 9;

  const unsigned char* Arow = Abase + (size_t)(bBase + ar) * Astride + kb + ac;
  const float* Wr = W + (size_t)(oBase + wr) * 1024 + kb + wk;

  {
    uint2 a = *(const uint2*)(Arow);
    float4 w0 = *(const float4*)(Wr);
    float4 w1 = *(const float4*)(Wr + 16 * 1024);
    float4 w2 = *(const float4*)(Wr + 32 * 1024);
    float4 w3 = *(const float4*)(Wr + 48 * 1024);
    wrA8(As[grp][0], ac, ar, a);
    wrW16(Ws[grp][0], wk, wr, w0, w1, w2, w3);
  }
  uint2 pa = *(const uint2*)(Arow + 32);
  float4 pw0 = *(const float4*)(Wr + 32);
  float4 pw1 = *(const float4*)(Wr + 32 + 16 * 1024);
  float4 pw2 = *(const float4*)(Wr + 32 + 32 * 1024);
  float4 pw3 = *(const float4*)(Wr + 32 + 48 * 1024);
  __syncthreads();

  int cb = 0;
#pragma unroll 1
  for (int kt = 0; kt < 16; ++kt) {
    uint2 na; float4 nw0, nw1, nw2, nw3;
    if (kt + 2 < 16) {
      const int ko = (kt + 2) << 5;
      na  = *(const uint2*)(Arow + ko);
      nw0 = *(const float4*)(Wr + ko);
      nw1 = *(const float4*)(Wr + ko + 16 * 1024);
      nw2 = *(const float4*)(Wr + ko + 32 * 1024);
      nw3 = *(const float4*)(Wr + ko + 48 * 1024);
    }
#pragma unroll
    for (int k = 0; k < 32; ++k) {
      const float4 a = *(const float4*)&As[grp][cb][k][tb4];
      const float4 w = *(const float4*)&Ws[grp][cb][k][to4];
      pan[0][0] = fmaf(a.x, w.x, pan[0][0]);
      pan[0][1] = fmaf(a.x, w.y, pan[0][1]);
      pan[0][2] = fmaf(a.x, w.z, pan[0][2]);
      pan[0][3] = fmaf(a.x, w.w, pan[0][3]);
      pan[1][0] = fmaf(a.y, w.x, pan[1][0]);
      pan[1][1] = fmaf(a.y, w.y, pan[1][1]);
      pan[1][2] = fmaf(a.y, w.z, pan[1][2]);
      pan[1][3] = fmaf(a.y, w.w, pan[1][3]);
      pan[2][0] = fmaf(a.z, w.x, pan[2][0]);
      pan[2][1] = fmaf(a.z, w.y, pan[2][1]);
      pan[2][2] = fmaf(a.z, w.z, pan[2][2]);
      pan[2][3] = fmaf(a.z, w.w, pan[2][3]);
      pan[3][0] = fmaf(a.w, w.x, pan[3][0]);
      pan[3][1] = fmaf(a.w, w.y, pan[3][1]);
      pan[3][2] = fmaf(a.w, w.z, pan[3][2]);
      pan[3][3] = fmaf(a.w, w.w, pan[3][3]);
    }
    if (kt + 1 < 16) {
      const int nb = cb ^ 1;
      wrA8(As[grp][nb], ac, ar, pa);
      wrW16(Ws[grp][nb], wk, wr, pw0, pw1, pw2, pw3);
    }
    if (kt + 2 < 16) { pa = na; pw0 = nw0; pw1 = nw1; pw2 = nw2; pw3 = nw3; }
    __syncthreads();
    cb ^= 1;
  }

  // fold: high panel -> LDS, low adds it (BLAS order: fadd(panLow, panHigh))
  float* foldp = &As[1][0][0][0];
  if (grp == 1) {
#pragma unroll
    for (int i = 0; i < 4; ++i) {
      float4 st; st.x = pan[i][0]; st.y = pan[i][1];
      st.z = pan[i][2]; st.w = pan[i][3];
      *(float4*)&foldp[(i * 128 + lt) * 4] = st;
    }
  }
  __syncthreads();
  if (grp == 0) {
#pragma unroll
    for (int i = 0; i < 4; ++i) {
      float4 h = *(const float4*)&foldp[(i * 128 + lt) * 4];
      pan[i][0] = __fadd_rn(pan[i][0], h.x);
      pan[i][1] = __fadd_rn(pan[i][1], h.y);
      pan[i][2] = __fadd_rn(pan[i][2], h.z);
      pan[i][3] = __fadd_rn(pan[i][3], h.w);
    }
  }
}

// ---- whole-K GEMM: K=512 (single panel, no fold), 256 thr, micro 4x2.
template<bool AFLOAT>
__device__ __forceinline__ void gemm_whole(
    const void* __restrict__ Abase, int Astride,
    const float* __restrict__ W,  // [o][512]
    int bBase, int oBase,
    float (&As)[2][2][32][32], float (&Ws)[2][2][32][68],
    float (&pan)[4][2])
{
  const int tid = threadIdx.x;
  const int ar = tid >> 3, ac4 = (tid & 7) << 2;
  const int wr = tid >> 2, wk2 = (tid & 3) << 3;
  const int tb4 = (tid >> 5) << 2;
  const int to2 = (tid & 31) << 1;

  const float* Af = (const float*)Abase + (size_t)(bBase + ar) * Astride + ac4;
  const unsigned char* Ab = (const unsigned char*)Abase + (size_t)(bBase + ar) * Astride + ac4;
  const float* Wr = W + (size_t)(oBase + wr) * 512 + wk2;

  {
    float4 w0 = *(const float4*)(Wr);
    float4 w1 = *(const float4*)(Wr + 4);
    if (AFLOAT) wrA4f(As[0][0], ac4, ar, *(const float4*)(Af));
    else        wrA4b(As[0][0], ac4, ar, *(const unsigned*)(Ab));
    wrW8(Ws[0][0], wk2, wr, w0, w1);
  }
  float4 paf; unsigned pab;
  if (AFLOAT) paf = *(const float4*)(Af + 32); else pab = *(const unsigned*)(Ab + 32);
  float4 pw0 = *(const float4*)(Wr + 32);
  float4 pw1 = *(const float4*)(Wr + 36);
  __syncthreads();

  int cb = 0;
#pragma unroll 1
  for (int kt = 0; kt < 16; ++kt) {
    float4 naf; unsigned nab; float4 nw0, nw1;
    if (kt + 2 < 16) {
      const int ko = (kt + 2) << 5;
      if (AFLOAT) naf = *(const float4*)(Af + ko); else nab = *(const unsigned*)(Ab + ko);
      nw0 = *(const float4*)(Wr + ko);
      nw1 = *(const float4*)(Wr + ko + 4);
    }
#pragma unroll
    for (int k = 0; k < 32; ++k) {
      const float4 a = *(const float4*)&As[0][cb][k][tb4];
      const float2 w = *(const float2*)&Ws[0][cb][k][to2];
      pan[0][0] = fmaf(a.x, w.x, pan[0][0]);
      pan[0][1] = fmaf(a.x, w.y, pan[0][1]);
      pan[1][0] = fmaf(a.y, w.x, pan[1][0]);
      pan[1][1] = fmaf(a.y, w.y, pan[1][1]);
      pan[2][0] = fmaf(a.z, w.x, pan[2][0]);
      pan[2][1] = fmaf(a.z, w.y, pan[2][1]);
      pan[3][0] = fmaf(a.w, w.x, pan[3][0]);
      pan[3][1] = fmaf(a.w, w.y, pan[3][1]);
    }
    if (kt + 1 < 16) {
      const int nb = cb ^ 1;
      if (AFLOAT) wrA4f(As[0][nb], ac4, ar, paf);
      else        wrA4b(As[0][nb], ac4, ar, pab);
      wrW8(Ws[0][nb], wk2, wr, pw0, pw1);
    }
    if (kt + 2 < 16) { paf = naf; pab = nab; pw0 = nw0; pw1 = nw1; }
    __syncthreads();
    cb ^= 1;
  }
}

// ---- one phase's work for one block (NO early returns; block-uniform) ----
__device__ __forceinline__ void do_phase(
    int g, int lb, int t, int p,
    const float* __restrict__ x,
    const float* __restrict__ W0, const float* __restrict__ W1,
    const float* __restrict__ W2a, const float* __restrict__ W2b,
    const float* __restrict__ W3, const float* __restrict__ W4,
    float* __restrict__ wf, float* __restrict__ out,
    float (&As)[2][2][32][32], float (&Ws)[2][2][32][68])
{
  float* cnt = wf + OFF_CNT;
  float* c2a = wf + OFF_C2A;
  unsigned char* sb = (unsigned char*)(wf + OFF_BYTE);
  const int cur = p & 1, prev = cur ^ 1;

  const int ntO = (g == 4) ? 8 : (g == 5) ? 2 : 16;
  const int N   = (g == 4) ? 512 : (g == 5) ? 128 : 1024;
  const int bBase = (lb / ntO) << 5;
  const int oBase = (lb % ntO) << 6;
  const int tid = threadIdx.x;

  if (g == 0 || g == 5) {
    float pan[4][2] = {{0.f,0.f},{0.f,0.f},{0.f,0.f},{0.f,0.f}};
    float alpha, vth; float* v;
    if (g == 0) {
      gemm_whole<true >(x + (size_t)t * 512, NT * 512, W0, bBase, oBase, As, Ws, pan);
      alpha = 0.90f; vth = 0.5f; v = wf + OFF_V0;
    } else {
      gemm_whole<false>(sb + BS3 + (size_t)prev * 65536, 512, W4, bBase, oBase, As, Ws, pan);
      alpha = 0.82f; vth = 0.8f; v = wf + OFF_VO;
    }
    const int tb4 = (tid >> 5) << 2;
    const int to2 = (tid & 31) << 1;
    unsigned char* sOut = sb + BS0 + (size_t)cur * 131072;
#pragma unroll
    for (int i = 0; i < 4; ++i) {
      const int b = bBase + tb4 + i;
      int si[2];
#pragma unroll
      for (int j = 0; j < 2; ++j) {
        const int o = oBase + to2 + j;
        float* vp = v + (size_t)b * N + o;
        float vv = __fadd_rn(__fmul_rn(alpha, *vp), pan[i][j]);
        int s = (vv >= vth) ? 1 : 0;
        float sf = (float)s;
        *vp = __fmul_rn(vv, __fsub_rn(1.0f, sf));
        si[j] = s;
        if (g == 5) {
          out[(size_t)b * (NT * 128) + (size_t)t * 128 + o] = sf;
          cnt[b * 128 + o] = __fadd_rn(cnt[b * 128 + o], sf);  // integer-exact
        }
      }
      if (g == 0) {
        *(unsigned short*)(sOut + (size_t)b * 1024 + oBase + to2) =
            (unsigned short)(si[0] | (si[1] << 8));
      }
    }
  } else {
    // split K=1024 stages: g1 (L1), g2 (2a), g3 (2b), g4 (L3)
    const unsigned char* Ab; const float* Wm;
    switch (g) {
      case 1: Ab = sb + BS0 + (size_t)prev * 131072; Wm = W1;  break;
      case 2: Ab = sb + BS1 + (size_t)prev * 131072; Wm = W2a; break;
      case 3: Ab = sb + BS2 + (size_t)prev * 131072; Wm = W2b; break;
      default: Ab = sb + BS2 + (size_t)prev * 131072; Wm = W3; break;
    }

    float pan[4][4];
#pragma unroll
    for (int i = 0; i < 4; ++i)
#pragma unroll
      for (int j = 0; j < 4; ++j) pan[i][j] = 0.f;

    gemm_split(Ab, 1024, Wm, bBase, oBase, As, Ws, pan);

    if (tid < 128) {  // only group 0 holds the folded result
      const int lt = tid;
      const int tb4 = (lt >> 4) << 2;
      const int to4 = (lt & 15) << 2;

      if (g == 2) {
        float* dst = c2a + (size_t)cur * 131072;
#pragma unroll
        for (int i = 0; i < 4; ++i) {
          const int b = bBase + tb4 + i;
          float4 st; st.x = pan[i][0]; st.y = pan[i][1];
          st.z = pan[i][2]; st.w = pan[i][3];
          *(float4*)(dst + (size_t)b * 1024 + oBase + to4) = st;
        }
      } else {
        float alpha; float* v; unsigned char* sOut;
        switch (g) {
          case 1: alpha = 0.95f; v = wf + OFF_V1; sOut = sb + BS1 + (size_t)cur * 131072; break;
          case 3: alpha = 0.93f; v = wf + OFF_V2; sOut = sb + BS2 + (size_t)cur * 131072; break;
          default: alpha = 0.90f; v = wf + OFF_V3; sOut = sb + BS3 + (size_t)cur * 65536; break;
        }
        const float* c2aPrev = c2a + (size_t)prev * 131072;
#pragma unroll
        for (int i = 0; i < 4; ++i) {
          const int b = bBase + tb4 + i;
          float cin[4];
          if (g == 3) {
            float4 ca = *(const float4*)(c2aPrev + (size_t)b * 1024 + oBase + to4);
            // reference: ONE __fadd_rn combining the two matmuls, W2a first
            cin[0] = __fadd_rn(ca.x, pan[i][0]);
            cin[1] = __fadd_rn(ca.y, pan[i][1]);
            cin[2] = __fadd_rn(ca.z, pan[i][2]);
            cin[3] = __fadd_rn(ca.w, pan[i][3]);
          } else {
            cin[0] = pan[i][0]; cin[1] = pan[i][1];
            cin[2] = pan[i][2]; cin[3] = pan[i][3];
          }
          unsigned packed = 0;
#pragma unroll
          for (int j = 0; j < 4; ++j) {
            const int o = oBase + to4 + j;
            float* vp = v + (size_t)b * N + o;
            float vv = __fadd_rn(__fmul_rn(alpha, *vp), cin[j]);
            int s = (vv >= 0.5f) ? 1 : 0;
            float sf = (float)s;
            *vp = __fmul_rn(vv, __fsub_rn(1.0f, sf));
            packed |= (unsigned)s << (8 * j);
          }
          *(unsigned*)(sOut + (size_t)b * N + oBase + to4) = packed;
        }
      }
    }
  }
}

// ---- persistent cooperative kernel: init -> 517 phases -> fin ----
__global__ __launch_bounds__(256, 2) void persist_kernel(
    const float* __restrict__ x,
    const float* __restrict__ W0, const float* __restrict__ W1,
    const float* __restrict__ W2a, const float* __restrict__ W2b,
    const float* __restrict__ W3, const float* __restrict__ W4,
    float* __restrict__ wf, float* __restrict__ out)
{
  cg::grid_group grid = cg::this_grid();
  __shared__ float As[2][2][32][32];
  __shared__ float Ws[2][2][32][68];

  // init: zero workspace (grid-stride)
  {
    size_t i = (size_t)blockIdx.x * blockDim.x + threadIdx.x;
    size_t stride = (size_t)gridDim.x * blockDim.x;
    for (size_t j = i; j < WS_FLOATS; j += stride) wf[j] = 0.0f;
  }
  grid.sync();

  // block -> stage decode (fixed across phases)
  const int blk = blockIdx.x;
  int g, lb, dt;
  if (blk < 64)       { g = 0; lb = blk;       dt = 0; }
  else if (blk < 128) { g = 1; lb = blk - 64;  dt = 1; }
  else if (blk < 192) { g = 2; lb = blk - 128; dt = 2; }
  else if (blk < 256) { g = 3; lb = blk - 192; dt = 3; }
  else if (blk < 288) { g = 4; lb = blk - 256; dt = 4; }
  else                { g = 5; lb = blk - 288; dt = 5; }

  for (int p = 0; p < NT + 5; ++p) {
    const int t = p - dt;
    if (t >= 0 && t < NT) {
      do_phase(g, lb, t, p, x, W0, W1, W2a, W2b, W3, W4, wf, out, As, Ws);
    }
    __syncthreads();
    grid.sync();
  }

  // fin: counts -> out tail (grid-stride)
  {
    size_t i = (size_t)blockIdx.x * blockDim.x + threadIdx.x;
    size_t stride = (size_t)gridDim.x * blockDim.x;
    for (size_t j = i; j < 16384; j += stride)
      out[(size_t)128 * NT * 128 + j] = wf[OFF_CNT + j];
  }
}

// ---------------------------------------------------------------------------
// -------------------- FALLBACK: round-15 multi-launch ----------------------
// ---------------------------------------------------------------------------

__global__ __launch_bounds__(256) void init_kernel(float* __restrict__ wf) {
  size_t i = (size_t)blockIdx.x * blockDim.x + threadIdx.x;
  size_t stride = (size_t)gridDim.x * blockDim.x;
  for (size_t j = i; j < WS_FLOATS; j += stride) wf[j] = 0.0f;
}

__global__ __launch_bounds__(256) void phase_kernel(
    const float* __restrict__ x,
    const float* __restrict__ W0, const float* __restrict__ W1,
    const float* __restrict__ W2a, const float* __restrict__ W2b,
    const float* __restrict__ W3, const float* __restrict__ W4,
    float* __restrict__ wf, float* __restrict__ out, int p)
{
  __shared__ float As[2][2][32][32];
  __shared__ float Ws[2][2][32][68];

  const int blk = blockIdx.x;
  int g, lb, dt;
  if (blk < 64)       { g = 0; lb = blk;       dt = 0; }
  else if (blk < 128) { g = 1; lb = blk - 64;  dt = 1; }
  else if (blk < 192) { g = 2; lb = blk - 128; dt = 2; }
  else if (blk < 256) { g = 3; lb = blk - 192; dt = 3; }
  else if (blk < 288) { g = 4; lb = blk - 256; dt = 4; }
  else                { g = 5; lb = blk - 288; dt = 5; }
  const int t = p - dt;
  if (t < 0 || t >= NT) return;

  do_phase(g, lb, t, p, x, W0, W1, W2a, W2b, W3, W4, wf, out, As, Ws);
}

__global__ __launch_bounds__(256) void fin_kernel(const float* __restrict__ counts,
                                                  float* __restrict__ out) {
  int i = blockIdx.x * blockDim.x + threadIdx.x;
  if (i < 128 * 128) out[(size_t)128 * NT * 128 + i] = counts[i];
}

// ---------------------------------------------------------------------------
// -------------------------------- launcher ---------------------------------
// ---------------------------------------------------------------------------

extern "C" void kernel_launch(void* const* d_in, const int* in_sizes, int n_in,
                              void* d_out, int out_size, void* d_ws, size_t ws_size,
                              hipStream_t stream) {
  const float* x   = (const float*)d_in[0];
  const float* W0  = (const float*)d_in[1];
  const float* W1  = (const float*)d_in[2];
  const float* W2a = (const float*)d_in[3];
  const float* W2b = (const float*)d_in[4];
  const float* W3  = (const float*)d_in[5];
  const float* W4  = (const float*)d_in[6];
  float* wf  = (float*)d_ws;
  float* out = (float*)d_out;

  void* args[9];
  args[0] = (void*)&x;
  args[1] = (void*)&W0;
  args[2] = (void*)&W1;
  args[3] = (void*)&W2a;
  args[4] = (void*)&W2b;
  args[5] = (void*)&W3;
  args[6] = (void*)&W4;
  args[7] = (void*)&wf;
  args[8] = (void*)&out;

  hipError_t e = hipLaunchCooperativeKernel(
      (const void*)persist_kernel, dim3(296), dim3(256), args, 0, stream);

  if (e != hipSuccess) {
    (void)hipGetLastError();  // clear sticky error, fall back to multi-launch
    init_kernel<<<512, 256, 0, stream>>>(wf);
    for (int p = 0; p < NT + 5; ++p) {
      phase_kernel<<<296, 256, 0, stream>>>(x, W0, W1, W2a, W2b, W3, W4, wf, out, p);
    }
    fin_kernel<<<64, 256, 0, stream>>>(wf + OFF_CNT, out);
  }
}

// Round 6
// 23730.301 us; speedup vs baseline: 3.2629x; 3.2629x over previous
//
#include <hip/hip_runtime.h>
#include <cstddef>

// SafetyReflexSNN: 5-layer LIF SNN, B=128, T=512.
//
// ROUND 17: PERSISTENT KERNEL + HAND-ROLLED AGENT-SCOPE BARRIER.
// Round-16 counters showed grid.sync() costs ~147 us/phase (WRITE 105 GB,
// FETCH 12.7 GB = full weight refetch from HBM every phase). This round:
// normal (non-cooperative) launch of 296 persistent blocks; per-phase sync =
// __syncthreads (drains stores) -> fence(RELEASE,"agent") [buffer_wbl2 sc1:
// dirty lines -> Infinity Cache] -> relaxed agent atomic arrive -> relaxed
// spin -> fence(ACQUIRE,"agent") [buffer_inv] -> __syncthreads. Weights
// refetch from IF (34 TB/s), never HBM; v-states/counts live in block-
// private LDS (blocks own fixed tiles across phases) so they never enter
// the coherence path. Deadlock-safe: 296 blocks <= 2/CU x 256 CU (LDS
// 68.6 KB <= 80 KB, launch_bounds(256,2) caps VGPR at 128); host verifies
// occupancy >= 2 blocks/CU else falls back to the proven multi-launch path.
//
// NUMERICS (absmax 0.0 inherited): per output element the op sequence is
// value-identical to rounds 11/14/15: ascending-k fmaf chain per panel;
// K=1024 combines panels with one __fadd_rn(low, high); layer-2 combine =
// one __fadd_rn(W2a_res, W2b_res); LIF = __fmul_rn / __fadd_rn / __fsub_rn;
// counts accumulated in ascending t. Only v/cnt STORAGE moved (LDS vs
// global) — same values, same rounding.

#define NB 128
#define NT 512
#define GRID_BLOCKS 296

// ---- workspace layout (floats) ----
enum : size_t {
  OFF_V0   = 0,                       // [128][1024]   (fallback path only)
  OFF_V1   = OFF_V0 + 131072,
  OFF_V2   = OFF_V1 + 131072,
  OFF_V3   = OFF_V2 + 131072,         // [128][512]
  OFF_VO   = OFF_V3 + 65536,          // [128][128]
  OFF_CNT  = OFF_VO + 16384,          // [128][128]
  OFF_C2A  = OFF_CNT + 16384,         // 2 x [128][1024] float
  OFF_BYTE = OFF_C2A + 262144,        // byte region starts here (float idx)
  WS_FLOATS = OFF_BYTE + 229376,      // 983040 floats = 3.93 MB
  OFF_BAR  = WS_FLOATS               // u64 barrier counter (8B aligned)
};
#define BS0 0
#define BS1 262144
#define BS2 524288
#define BS3 786432

// ---- LDS staging helpers (transposed layouts) ----
__device__ __forceinline__ void wrA8(float (&A)[32][32], int ac, int ar, uint2 u) {
  A[ac + 0][ar] = (float)(u.x & 0xff);
  A[ac + 1][ar] = (float)((u.x >> 8) & 0xff);
  A[ac + 2][ar] = (float)((u.x >> 16) & 0xff);
  A[ac + 3][ar] = (float)(u.x >> 24);
  A[ac + 4][ar] = (float)(u.y & 0xff);
  A[ac + 5][ar] = (float)((u.y >> 8) & 0xff);
  A[ac + 6][ar] = (float)((u.y >> 16) & 0xff);
  A[ac + 7][ar] = (float)(u.y >> 24);
}
__device__ __forceinline__ void wrW16(float (&Wt)[32][68], int wk, int wr,
    const float4& w0, const float4& w1, const float4& w2, const float4& w3) {
  Wt[wk + 0][wr]      = w0.x; Wt[wk + 1][wr]      = w0.y;
  Wt[wk + 2][wr]      = w0.z; Wt[wk + 3][wr]      = w0.w;
  Wt[wk + 0][wr + 16] = w1.x; Wt[wk + 1][wr + 16] = w1.y;
  Wt[wk + 2][wr + 16] = w1.z; Wt[wk + 3][wr + 16] = w1.w;
  Wt[wk + 0][wr + 32] = w2.x; Wt[wk + 1][wr + 32] = w2.y;
  Wt[wk + 2][wr + 32] = w2.z; Wt[wk + 3][wr + 32] = w2.w;
  Wt[wk + 0][wr + 48] = w3.x; Wt[wk + 1][wr + 48] = w3.y;
  Wt[wk + 2][wr + 48] = w3.z; Wt[wk + 3][wr + 48] = w3.w;
}
__device__ __forceinline__ void wrA4f(float (&A)[32][32], int ac4, int ar, float4 f) {
  A[ac4 + 0][ar] = f.x; A[ac4 + 1][ar] = f.y;
  A[ac4 + 2][ar] = f.z; A[ac4 + 3][ar] = f.w;
}
__device__ __forceinline__ void wrA4b(float (&A)[32][32], int ac4, int ar, unsigned u) {
  A[ac4 + 0][ar] = (float)(u & 0xff);
  A[ac4 + 1][ar] = (float)((u >> 8) & 0xff);
  A[ac4 + 2][ar] = (float)((u >> 16) & 0xff);
  A[ac4 + 3][ar] = (float)(u >> 24);
}
__device__ __forceinline__ void wrW8(float (&Wt)[32][68], int wk2, int wr,
    const float4& w0, const float4& w1) {
  Wt[wk2 + 0][wr] = w0.x; Wt[wk2 + 1][wr] = w0.y;
  Wt[wk2 + 2][wr] = w0.z; Wt[wk2 + 3][wr] = w0.w;
  Wt[wk2 + 4][wr] = w1.x; Wt[wk2 + 5][wr] = w1.y;
  Wt[wk2 + 6][wr] = w1.z; Wt[wk2 + 7][wr] = w1.w;
}

// ---- split GEMM: K=1024, 256 thr, wave-group panel split at k=512.
__device__ __forceinline__ void gemm_split(
    const unsigned char* __restrict__ Abase, int Astride,
    const float* __restrict__ W,  // [o][1024]
    int bBase, int oBase,
    float (&As)[2][2][32][32], float (&Ws)[2][2][32][68],
    float (&pan)[4][4])
{
  const int tid = threadIdx.x;
  const int grp = tid >> 7, lt = tid & 127;
  const int ar = lt >> 2, ac = (lt & 3) << 3;
  const int wr = lt >> 3, wk = (lt & 7) << 2;
  const int tb4 = (lt >> 4) << 2;
  const int to4 = (lt & 15) << 2;
  const int kb = grp << 9;

  const unsigned char* Arow = Abase + (size_t)(bBase + ar) * Astride + kb + ac;
  const float* Wr = W + (size_t)(oBase + wr) * 1024 + kb + wk;

  {
    uint2 a = *(const uint2*)(Arow);
    float4 w0 = *(const float4*)(Wr);
    float4 w1 = *(const float4*)(Wr + 16 * 1024);
    float4 w2 = *(const float4*)(Wr + 32 * 1024);
    float4 w3 = *(const float4*)(Wr + 48 * 1024);
    wrA8(As[grp][0], ac, ar, a);
    wrW16(Ws[grp][0], wk, wr, w0, w1, w2, w3);
  }
  uint2 pa = *(const uint2*)(Arow + 32);
  float4 pw0 = *(const float4*)(Wr + 32);
  float4 pw1 = *(const float4*)(Wr + 32 + 16 * 1024);
  float4 pw2 = *(const float4*)(Wr + 32 + 32 * 1024);
  float4 pw3 = *(const float4*)(Wr + 32 + 48 * 1024);
  __syncthreads();

  int cb = 0;
#pragma unroll 1
  for (int kt = 0; kt < 16; ++kt) {
    uint2 na; float4 nw0, nw1, nw2, nw3;
    if (kt + 2 < 16) {
      const int ko = (kt + 2) << 5;
      na  = *(const uint2*)(Arow + ko);
      nw0 = *(const float4*)(Wr + ko);
      nw1 = *(const float4*)(Wr + ko + 16 * 1024);
      nw2 = *(const float4*)(Wr + ko + 32 * 1024);
      nw3 = *(const float4*)(Wr + ko + 48 * 1024);
    }
#pragma unroll
    for (int k = 0; k < 32; ++k) {
      const float4 a = *(const float4*)&As[grp][cb][k][tb4];
      const float4 w = *(const float4*)&Ws[grp][cb][k][to4];
      pan[0][0] = fmaf(a.x, w.x, pan[0][0]);
      pan[0][1] = fmaf(a.x, w.y, pan[0][1]);
      pan[0][2] = fmaf(a.x, w.z, pan[0][2]);
      pan[0][3] = fmaf(a.x, w.w, pan[0][3]);
      pan[1][0] = fmaf(a.y, w.x, pan[1][0]);
      pan[1][1] = fmaf(a.y, w.y, pan[1][1]);
      pan[1][2] = fmaf(a.y, w.z, pan[1][2]);
      pan[1][3] = fmaf(a.y, w.w, pan[1][3]);
      pan[2][0] = fmaf(a.z, w.x, pan[2][0]);
      pan[2][1] = fmaf(a.z, w.y, pan[2][1]);
      pan[2][2] = fmaf(a.z, w.z, pan[2][2]);
      pan[2][3] = fmaf(a.z, w.w, pan[2][3]);
      pan[3][0] = fmaf(a.w, w.x, pan[3][0]);
      pan[3][1] = fmaf(a.w, w.y, pan[3][1]);
      pan[3][2] = fmaf(a.w, w.z, pan[3][2]);
      pan[3][3] = fmaf(a.w, w.w, pan[3][3]);
    }
    if (kt + 1 < 16) {
      const int nb = cb ^ 1;
      wrA8(As[grp][nb], ac, ar, pa);
      wrW16(Ws[grp][nb], wk, wr, pw0, pw1, pw2, pw3);
    }
    if (kt + 2 < 16) { pa = na; pw0 = nw0; pw1 = nw1; pw2 = nw2; pw3 = nw3; }
    __syncthreads();
    cb ^= 1;
  }

  // fold: high panel -> LDS, low adds it (BLAS order: fadd(panLow, panHigh))
  float* foldp = &As[1][0][0][0];
  if (grp == 1) {
#pragma unroll
    for (int i = 0; i < 4; ++i) {
      float4 st; st.x = pan[i][0]; st.y = pan[i][1];
      st.z = pan[i][2]; st.w = pan[i][3];
      *(float4*)&foldp[(i * 128 + lt) * 4] = st;
    }
  }
  __syncthreads();
  if (grp == 0) {
#pragma unroll
    for (int i = 0; i < 4; ++i) {
      float4 h = *(const float4*)&foldp[(i * 128 + lt) * 4];
      pan[i][0] = __fadd_rn(pan[i][0], h.x);
      pan[i][1] = __fadd_rn(pan[i][1], h.y);
      pan[i][2] = __fadd_rn(pan[i][2], h.z);
      pan[i][3] = __fadd_rn(pan[i][3], h.w);
    }
  }
}

// ---- whole-K GEMM: K=512 (single panel, no fold), 256 thr, micro 4x2.
template<bool AFLOAT>
__device__ __forceinline__ void gemm_whole(
    const void* __restrict__ Abase, int Astride,
    const float* __restrict__ W,  // [o][512]
    int bBase, int oBase,
    float (&As)[2][2][32][32], float (&Ws)[2][2][32][68],
    float (&pan)[4][2])
{
  const int tid = threadIdx.x;
  const int ar = tid >> 3, ac4 = (tid & 7) << 2;
  const int wr = tid >> 2, wk2 = (tid & 3) << 3;
  const int tb4 = (tid >> 5) << 2;
  const int to2 = (tid & 31) << 1;

  const float* Af = (const float*)Abase + (size_t)(bBase + ar) * Astride + ac4;
  const unsigned char* Ab = (const unsigned char*)Abase + (size_t)(bBase + ar) * Astride + ac4;
  const float* Wr = W + (size_t)(oBase + wr) * 512 + wk2;

  {
    float4 w0 = *(const float4*)(Wr);
    float4 w1 = *(const float4*)(Wr + 4);
    if (AFLOAT) wrA4f(As[0][0], ac4, ar, *(const float4*)(Af));
    else        wrA4b(As[0][0], ac4, ar, *(const unsigned*)(Ab));
    wrW8(Ws[0][0], wk2, wr, w0, w1);
  }
  float4 paf; unsigned pab;
  if (AFLOAT) paf = *(const float4*)(Af + 32); else pab = *(const unsigned*)(Ab + 32);
  float4 pw0 = *(const float4*)(Wr + 32);
  float4 pw1 = *(const float4*)(Wr + 36);
  __syncthreads();

  int cb = 0;
#pragma unroll 1
  for (int kt = 0; kt < 16; ++kt) {
    float4 naf; unsigned nab; float4 nw0, nw1;
    if (kt + 2 < 16) {
      const int ko = (kt + 2) << 5;
      if (AFLOAT) naf = *(const float4*)(Af + ko); else nab = *(const unsigned*)(Ab + ko);
      nw0 = *(const float4*)(Wr + ko);
      nw1 = *(const float4*)(Wr + ko + 4);
    }
#pragma unroll
    for (int k = 0; k < 32; ++k) {
      const float4 a = *(const float4*)&As[0][cb][k][tb4];
      const float2 w = *(const float2*)&Ws[0][cb][k][to2];
      pan[0][0] = fmaf(a.x, w.x, pan[0][0]);
      pan[0][1] = fmaf(a.x, w.y, pan[0][1]);
      pan[1][0] = fmaf(a.y, w.x, pan[1][0]);
      pan[1][1] = fmaf(a.y, w.y, pan[1][1]);
      pan[2][0] = fmaf(a.z, w.x, pan[2][0]);
      pan[2][1] = fmaf(a.z, w.y, pan[2][1]);
      pan[3][0] = fmaf(a.w, w.x, pan[3][0]);
      pan[3][1] = fmaf(a.w, w.y, pan[3][1]);
    }
    if (kt + 1 < 16) {
      const int nb = cb ^ 1;
      if (AFLOAT) wrA4f(As[0][nb], ac4, ar, paf);
      else        wrA4b(As[0][nb], ac4, ar, pab);
      wrW8(Ws[0][nb], wk2, wr, pw0, pw1);
    }
    if (kt + 2 < 16) { paf = naf; pab = nab; pw0 = nw0; pw1 = nw1; }
    __syncthreads();
    cb ^= 1;
  }
}

// ---- one phase's work for one block. PERSIST: v/cnt in vpriv (LDS slice,
// 16 floats per thread: [0..7]=v for 4x2 stages or [0..15] for 4x4; g5 cnt
// in [8..15]). !PERSIST: v/cnt in global wf (round-15 layout).
template<bool PERSIST>
__device__ __forceinline__ void do_phase(
    int g, int lb, int t, int p,
    const float* __restrict__ x,
    const float* __restrict__ W0, const float* __restrict__ W1,
    const float* __restrict__ W2a, const float* __restrict__ W2b,
    const float* __restrict__ W3, const float* __restrict__ W4,
    float* __restrict__ wf, float* __restrict__ out,
    float (&As)[2][2][32][32], float (&Ws)[2][2][32][68],
    float* __restrict__ vpriv)
{
  float* cnt = wf + OFF_CNT;
  float* c2a = wf + OFF_C2A;
  unsigned char* sb = (unsigned char*)(wf + OFF_BYTE);
  const int cur = p & 1, prev = cur ^ 1;

  const int ntO = (g == 4) ? 8 : (g == 5) ? 2 : 16;
  const int N   = (g == 4) ? 512 : (g == 5) ? 128 : 1024;
  const int bBase = (lb / ntO) << 5;
  const int oBase = (lb % ntO) << 6;
  const int tid = threadIdx.x;

  if (g == 0 || g == 5) {
    float pan[4][2] = {{0.f,0.f},{0.f,0.f},{0.f,0.f},{0.f,0.f}};
    float alpha, vth; float* v;
    if (g == 0) {
      gemm_whole<true >(x + (size_t)t * 512, NT * 512, W0, bBase, oBase, As, Ws, pan);
      alpha = 0.90f; vth = 0.5f; v = wf + OFF_V0;
    } else {
      gemm_whole<false>(sb + BS3 + (size_t)prev * 65536, 512, W4, bBase, oBase, As, Ws, pan);
      alpha = 0.82f; vth = 0.8f; v = wf + OFF_VO;
    }
    const int tb4 = (tid >> 5) << 2;
    const int to2 = (tid & 31) << 1;
    unsigned char* sOut = sb + BS0 + (size_t)cur * 131072;
#pragma unroll
    for (int i = 0; i < 4; ++i) {
      const int b = bBase + tb4 + i;
      int si[2];
#pragma unroll
      for (int j = 0; j < 2; ++j) {
        const int o = oBase + to2 + j;
        float vold;
        if (PERSIST) vold = vpriv[i * 2 + j];
        else         vold = v[(size_t)b * N + o];
        float vv = __fadd_rn(__fmul_rn(alpha, vold), pan[i][j]);
        int s = (vv >= vth) ? 1 : 0;
        float sf = (float)s;
        float nv = __fmul_rn(vv, __fsub_rn(1.0f, sf));
        if (PERSIST) vpriv[i * 2 + j] = nv;
        else         v[(size_t)b * N + o] = nv;
        si[j] = s;
        if (g == 5) {
          out[(size_t)b * (NT * 128) + (size_t)t * 128 + o] = sf;
          if (PERSIST) vpriv[8 + i * 2 + j] = __fadd_rn(vpriv[8 + i * 2 + j], sf);
          else         cnt[b * 128 + o] = __fadd_rn(cnt[b * 128 + o], sf);
        }
      }
      if (g == 0) {
        *(unsigned short*)(sOut + (size_t)b * 1024 + oBase + to2) =
            (unsigned short)(si[0] | (si[1] << 8));
      }
    }
  } else {
    // split K=1024 stages: g1 (L1), g2 (2a), g3 (2b), g4 (L3)
    const unsigned char* Ab; const float* Wm;
    switch (g) {
      case 1: Ab = sb + BS0 + (size_t)prev * 131072; Wm = W1;  break;
      case 2: Ab = sb + BS1 + (size_t)prev * 131072; Wm = W2a; break;
      case 3: Ab = sb + BS2 + (size_t)prev * 131072; Wm = W2b; break;
      default: Ab = sb + BS2 + (size_t)prev * 131072; Wm = W3; break;
    }

    float pan[4][4];
#pragma unroll
    for (int i = 0; i < 4; ++i)
#pragma unroll
      for (int j = 0; j < 4; ++j) pan[i][j] = 0.f;

    gemm_split(Ab, 1024, Wm, bBase, oBase, As, Ws, pan);

    if (tid < 128) {  // only group 0 holds the folded result
      const int lt = tid;
      const int tb4 = (lt >> 4) << 2;
      const int to4 = (lt & 15) << 2;

      if (g == 2) {
        float* dst = c2a + (size_t)cur * 131072;
#pragma unroll
        for (int i = 0; i < 4; ++i) {
          const int b = bBase + tb4 + i;
          float4 st; st.x = pan[i][0]; st.y = pan[i][1];
          st.z = pan[i][2]; st.w = pan[i][3];
          *(float4*)(dst + (size_t)b * 1024 + oBase + to4) = st;
        }
      } else {
        float alpha; float* v; unsigned char* sOut;
        switch (g) {
          case 1: alpha = 0.95f; v = wf + OFF_V1; sOut = sb + BS1 + (size_t)cur * 131072; break;
          case 3: alpha = 0.93f; v = wf + OFF_V2; sOut = sb + BS2 + (size_t)cur * 131072; break;
          default: alpha = 0.90f; v = wf + OFF_V3; sOut = sb + BS3 + (size_t)cur * 65536; break;
        }
        const float* c2aPrev = c2a + (size_t)prev * 131072;
#pragma unroll
        for (int i = 0; i < 4; ++i) {
          const int b = bBase + tb4 + i;
          float cin[4];
          if (g == 3) {
            float4 ca = *(const float4*)(c2aPrev + (size_t)b * 1024 + oBase + to4);
            // reference: ONE __fadd_rn combining the two matmuls, W2a first
            cin[0] = __fadd_rn(ca.x, pan[i][0]);
            cin[1] = __fadd_rn(ca.y, pan[i][1]);
            cin[2] = __fadd_rn(ca.z, pan[i][2]);
            cin[3] = __fadd_rn(ca.w, pan[i][3]);
          } else {
            cin[0] = pan[i][0]; cin[1] = pan[i][1];
            cin[2] = pan[i][2]; cin[3] = pan[i][3];
          }
          unsigned packed = 0;
#pragma unroll
          for (int j = 0; j < 4; ++j) {
            const int o = oBase + to4 + j;
            float vold;
            if (PERSIST) vold = vpriv[i * 4 + j];
            else         vold = v[(size_t)b * N + o];
            float vv = __fadd_rn(__fmul_rn(alpha, vold), cin[j]);
            int s = (vv >= 0.5f) ? 1 : 0;
            float sf = (float)s;
            float nv = __fmul_rn(vv, __fsub_rn(1.0f, sf));
            if (PERSIST) vpriv[i * 4 + j] = nv;
            else         v[(size_t)b * N + o] = nv;
            packed |= (unsigned)s << (8 * j);
          }
          *(unsigned*)(sOut + (size_t)b * N + oBase + to4) = packed;
        }
      }
    }
  }
}

// ---- pre kernel (separate launch): zero spike/c2a region + barrier ----
__global__ __launch_bounds__(256) void pre_kernel(float* __restrict__ wf) {
  size_t i = (size_t)blockIdx.x * blockDim.x + threadIdx.x;
  size_t stride = (size_t)gridDim.x * blockDim.x;
  for (size_t j = i; j < WS_FLOATS + 2; j += stride) wf[j] = 0.0f;
}

// ---- persistent kernel with custom agent-scope barrier ----
__global__ __launch_bounds__(256, 2) void persist2(
    const float* __restrict__ x,
    const float* __restrict__ W0, const float* __restrict__ W1,
    const float* __restrict__ W2a, const float* __restrict__ W2b,
    const float* __restrict__ W3, const float* __restrict__ W4,
    float* __restrict__ wf, float* __restrict__ out)
{
  __shared__ float As[2][2][32][32];   // 16 KB
  __shared__ float Ws[2][2][32][68];   // 34.8 KB
  __shared__ float vLds[256][17];      // 17.4 KB: per-thread v (16) + pad

  unsigned long long* bar = (unsigned long long*)(wf + OFF_BAR);
  const int tid = threadIdx.x;
  float* vpriv = &vLds[tid][0];
#pragma unroll
  for (int i = 0; i < 16; ++i) vpriv[i] = 0.0f;

  // block -> stage decode (fixed across phases; block owns its tile + v)
  const int blk = blockIdx.x;
  int g, lb, dt;
  if (blk < 64)       { g = 0; lb = blk;       dt = 0; }
  else if (blk < 128) { g = 1; lb = blk - 64;  dt = 1; }
  else if (blk < 192) { g = 2; lb = blk - 128; dt = 2; }
  else if (blk < 256) { g = 3; lb = blk - 192; dt = 3; }
  else if (blk < 288) { g = 4; lb = blk - 256; dt = 4; }
  else                { g = 5; lb = blk - 288; dt = 5; }

  const unsigned long long nblk = (unsigned long long)gridDim.x;

  for (int p = 0; p < NT + 5; ++p) {
    const int t = p - dt;
    if (t >= 0 && t < NT) {
      do_phase<true>(g, lb, t, p, x, W0, W1, W2a, W2b, W3, W4, wf, out,
                     As, Ws, vpriv);
    }
    __syncthreads();  // drains every wave's vmem stores (compiler waitcnt)
    if (tid == 0) {
      // push this XCD's dirty lines (spikes/c2a) to Infinity Cache
      __builtin_amdgcn_fence(__ATOMIC_RELEASE, "agent");
      __hip_atomic_fetch_add(bar, 1ULL, __ATOMIC_RELAXED,
                             __HIP_MEMORY_SCOPE_AGENT);
      const unsigned long long tgt = (unsigned long long)(p + 1) * nblk;
      while (__hip_atomic_load(bar, __ATOMIC_RELAXED,
                               __HIP_MEMORY_SCOPE_AGENT) < tgt) {
        __builtin_amdgcn_s_sleep(2);
      }
      // drop stale L1/L2 lines so next phase reads fresh data from IF
      __builtin_amdgcn_fence(__ATOMIC_ACQUIRE, "agent");
    }
    __syncthreads();
  }

  // final: g5 blocks write their register-accumulated counts
  if (g == 5) {
    const int tb4 = (tid >> 5) << 2;
    const int to2 = (tid & 31) << 1;
    const int bBase = (lb / 2) << 5;
    const int oBase = (lb % 2) << 6;
#pragma unroll
    for (int i = 0; i < 4; ++i)
#pragma unroll
      for (int j = 0; j < 2; ++j)
        out[(size_t)128 * NT * 128 + (size_t)(bBase + tb4 + i) * 128 +
            oBase + to2 + j] = vpriv[8 + i * 2 + j];
  }
}

// ---------------------------------------------------------------------------
// -------------------- FALLBACK: round-15 multi-launch ----------------------
// ---------------------------------------------------------------------------

__global__ __launch_bounds__(256) void init_kernel(float* __restrict__ wf) {
  size_t i = (size_t)blockIdx.x * blockDim.x + threadIdx.x;
  size_t stride = (size_t)gridDim.x * blockDim.x;
  for (size_t j = i; j < WS_FLOATS; j += stride) wf[j] = 0.0f;
}

__global__ __launch_bounds__(256) void phase_kernel(
    const float* __restrict__ x,
    const float* __restrict__ W0, const float* __restrict__ W1,
    const float* __restrict__ W2a, const float* __restrict__ W2b,
    const float* __restrict__ W3, const float* __restrict__ W4,
    float* __restrict__ wf, float* __restrict__ out, int p)
{
  __shared__ float As[2][2][32][32];
  __shared__ float Ws[2][2][32][68];

  const int blk = blockIdx.x;
  int g, lb, dt;
  if (blk < 64)       { g = 0; lb = blk;       dt = 0; }
  else if (blk < 128) { g = 1; lb = blk - 64;  dt = 1; }
  else if (blk < 192) { g = 2; lb = blk - 128; dt = 2; }
  else if (blk < 256) { g = 3; lb = blk - 192; dt = 3; }
  else if (blk < 288) { g = 4; lb = blk - 256; dt = 4; }
  else                { g = 5; lb = blk - 288; dt = 5; }
  const int t = p - dt;
  if (t < 0 || t >= NT) return;

  float vdummy[16];
  do_phase<false>(g, lb, t, p, x, W0, W1, W2a, W2b, W3, W4, wf, out,
                  As, Ws, vdummy);
}

__global__ __launch_bounds__(256) void fin_kernel(const float* __restrict__ counts,
                                                  float* __restrict__ out) {
  int i = blockIdx.x * blockDim.x + threadIdx.x;
  if (i < 128 * 128) out[(size_t)128 * NT * 128 + i] = counts[i];
}

// ---------------------------------------------------------------------------
// -------------------------------- launcher ---------------------------------
// ---------------------------------------------------------------------------

extern "C" void kernel_launch(void* const* d_in, const int* in_sizes, int n_in,
                              void* d_out, int out_size, void* d_ws, size_t ws_size,
                              hipStream_t stream) {
  const float* x   = (const float*)d_in[0];
  const float* W0  = (const float*)d_in[1];
  const float* W1  = (const float*)d_in[2];
  const float* W2a = (const float*)d_in[3];
  const float* W2b = (const float*)d_in[4];
  const float* W3  = (const float*)d_in[5];
  const float* W4  = (const float*)d_in[6];
  float* wf  = (float*)d_ws;
  float* out = (float*)d_out;

  // persistence requires all 296 blocks co-resident: need >= 2 blocks/CU.
  int maxBlocksPerCU = 0;
  hipError_t qe = hipOccupancyMaxActiveBlocksPerMultiprocessor(
      &maxBlocksPerCU, persist2, 256, 0);
  const bool wsOK = ws_size >= (WS_FLOATS + 2) * sizeof(float);

  if (qe == hipSuccess && maxBlocksPerCU >= 2 && wsOK) {
    pre_kernel<<<256, 256, 0, stream>>>(wf);
    persist2<<<GRID_BLOCKS, 256, 0, stream>>>(x, W0, W1, W2a, W2b, W3, W4,
                                              wf, out);
  } else {
    (void)hipGetLastError();
    init_kernel<<<512, 256, 0, stream>>>(wf);
    for (int p = 0; p < NT + 5; ++p) {
      phase_kernel<<<296, 256, 0, stream>>>(x, W0, W1, W2a, W2b, W3, W4, wf, out, p);
    }
    fin_kernel<<<64, 256, 0, stream>>>(wf + OFF_CNT, out);
  }
}

// Round 7
// 19648.056 us; speedup vs baseline: 3.9408x; 1.2078x over previous
//
#include <hip/hip_runtime.h>
#include <cstddef>

// SafetyReflexSNN: 5-layer LIF SNN, B=128, T=512.
//
// ROUND 18: FENCE-FREE PERSISTENT PIPELINE.
// Round-17 counters: WRITE 91 GB / FETCH 10.3 GB / VALUBusy 9% -> the
// agent fences (buffer_wbl2 + buffer_inv) flushed the ENTIRE L2 every
// phase to sync ~1 MB of spikes. This round:
//  - Cross-block data (spikes, c2a) moves via RELAXED AGENT-SCOPE atomic
//    load/store (sc1 ops: store writes through to IF, load reads at IF).
//    No fences anywhere -> weights stay L2-resident for all 517 phases.
//  - Barrier: syncthreads (drains vmcnt) -> per-block arrive slot (plain
//    sc1 store, no RMW contention) -> block 0 polls 512 slots with 256
//    threads -> release flag -> spin. ~1-2 us.
//  - Load balance: EXACTLY 512 blocks = 2/CU uniform, ~4096 FMA/thread:
//    g0=64 (L0 tile 32x64 + L4 one-elem-per-thread piggyback),
//    g1/g2/g3=128 (tile 32x32, wave-group K-split at k=512 BLAS panel),
//    g4=64 (L3 tile 32x32 split). LDS ~46 KB -> 2 blocks/CU.
//
// NUMERICS (absmax 0.0 inherited): identical op sequences: ascending-k
// fmaf chain per panel; K=1024 folds with one __fadd_rn(low, high);
// layer-2 combine = one __fadd_rn(W2a_res, W2b_res); LIF = __fmul_rn /
// __fadd_rn / __fsub_rn; counts in ascending t.

#define NB 128
#define NT 512
#define NBLK 512

// ---- workspace layout (floats) ----
enum : size_t {
  OFF_V0   = 0,                       // fallback-only state
  OFF_V1   = OFF_V0 + 131072,
  OFF_V2   = OFF_V1 + 131072,
  OFF_V3   = OFF_V2 + 131072,
  OFF_VO   = OFF_V3 + 65536,
  OFF_CNT  = OFF_VO + 16384,
  OFF_C2A  = OFF_CNT + 16384,         // 2 x [128][1024] float
  OFF_BYTE = OFF_C2A + 262144,        // byte region (float idx)
  WS_FLOATS = OFF_BYTE + 229376,      // 983040 floats
  OFF_ARR  = WS_FLOATS,               // u32 arrive[512*16] (64B spacing)
  OFF_FLAGF = OFF_ARR + 8192,         // u32 release flag
  WS_TOTAL = OFF_FLAGF + 16
};
#define BS0 0
#define BS1 262144
#define BS2 524288
#define BS3 786432

// ---- agent-scope (sc1) relaxed transport helpers ----
__device__ __forceinline__ void st_u16_agent(unsigned char* p, unsigned short v) {
  __hip_atomic_store((unsigned short*)p, v, __ATOMIC_RELAXED, __HIP_MEMORY_SCOPE_AGENT);
}
__device__ __forceinline__ unsigned long long ld_u64_agent(const unsigned char* p) {
  return __hip_atomic_load((const unsigned long long*)p, __ATOMIC_RELAXED, __HIP_MEMORY_SCOPE_AGENT);
}
__device__ __forceinline__ void st_u64_agent(void* p, unsigned long long v) {
  __hip_atomic_store((unsigned long long*)p, v, __ATOMIC_RELAXED, __HIP_MEMORY_SCOPE_AGENT);
}
__device__ __forceinline__ unsigned long long ld_u64_agentf(const float* p) {
  return __hip_atomic_load((const unsigned long long*)p, __ATOMIC_RELAXED, __HIP_MEMORY_SCOPE_AGENT);
}
__device__ __forceinline__ unsigned ld_u32_agent(const unsigned* p) {
  return __hip_atomic_load(p, __ATOMIC_RELAXED, __HIP_MEMORY_SCOPE_AGENT);
}
__device__ __forceinline__ void st_u32_agent(unsigned* p, unsigned v) {
  __hip_atomic_store(p, v, __ATOMIC_RELAXED, __HIP_MEMORY_SCOPE_AGENT);
}

union F2U { float2 f; unsigned long long u; };

__device__ __forceinline__ void unpack8(unsigned long long v, float* f) {
  unsigned lo = (unsigned)v, hi = (unsigned)(v >> 32);
  f[0] = (float)(lo & 0xff); f[1] = (float)((lo >> 8) & 0xff);
  f[2] = (float)((lo >> 16) & 0xff); f[3] = (float)(lo >> 24);
  f[4] = (float)(hi & 0xff); f[5] = (float)((hi >> 8) & 0xff);
  f[6] = (float)((hi >> 16) & 0xff); f[7] = (float)(hi >> 24);
}

// ---- split GEMM: tile 32b x 32o, K=1024 in 2 wave-group panels of 512.
// Group LDS: As 2buf x [32k][32b] (1024 f each), Ws 2buf x [32k][36] (1152 f).
__device__ __forceinline__ void gemm_split32(
    const unsigned char* __restrict__ Abase,  // byte spikes, row stride 1024
    const float* __restrict__ W,              // [o][1024]
    int bBase, int oBase, int grp, int lt,
    float* AsG, float* WsG, float acc[4][2])
{
  const int ar = lt >> 2, ac = (lt & 3) << 3;   // A: row ar, 8 k-bytes
  const int wr = lt >> 2, wk = (lt & 3) << 3;   // W: o-row wr, 8 k
  const int tb4 = (lt >> 4) << 2;               // compute: 4 b
  const int to2 = (lt & 15) << 1;               // compute: 2 o
  const int kb = grp << 9;

  const unsigned char* Arow = Abase + (size_t)(bBase + ar) * 1024 + kb + ac;
  const float* Wr = W + (size_t)(oBase + wr) * 1024 + kb + wk;

  {  // stage k-tile 0 -> buf 0
    float a[8]; unpack8(ld_u64_agent(Arow), a);
    float4 w0 = *(const float4*)(Wr);
    float4 w1 = *(const float4*)(Wr + 4);
#pragma unroll
    for (int i = 0; i < 8; ++i) AsG[(ac + i) * 32 + ar] = a[i];
    WsG[(wk+0)*36+wr] = w0.x; WsG[(wk+1)*36+wr] = w0.y;
    WsG[(wk+2)*36+wr] = w0.z; WsG[(wk+3)*36+wr] = w0.w;
    WsG[(wk+4)*36+wr] = w1.x; WsG[(wk+5)*36+wr] = w1.y;
    WsG[(wk+6)*36+wr] = w1.z; WsG[(wk+7)*36+wr] = w1.w;
  }
  unsigned long long pa = ld_u64_agent(Arow + 32);
  float4 pw0 = *(const float4*)(Wr + 32);
  float4 pw1 = *(const float4*)(Wr + 36);
  __syncthreads();

  int cb = 0;
#pragma unroll 1
  for (int kt = 0; kt < 16; ++kt) {
    unsigned long long na; float4 nw0, nw1;
    if (kt + 2 < 16) {  // 2-deep prefetch
      const int ko = (kt + 2) << 5;
      na  = ld_u64_agent(Arow + ko);
      nw0 = *(const float4*)(Wr + ko);
      nw1 = *(const float4*)(Wr + ko + 4);
    }
    const float* Asb = AsG + cb * 1024;
    const float* Wsb = WsG + cb * 1152;
#pragma unroll
    for (int k = 0; k < 32; ++k) {
      const float4 a = *(const float4*)&Asb[k * 32 + tb4];
      const float2 w = *(const float2*)&Wsb[k * 36 + to2];
      acc[0][0] = fmaf(a.x, w.x, acc[0][0]);
      acc[0][1] = fmaf(a.x, w.y, acc[0][1]);
      acc[1][0] = fmaf(a.y, w.x, acc[1][0]);
      acc[1][1] = fmaf(a.y, w.y, acc[1][1]);
      acc[2][0] = fmaf(a.z, w.x, acc[2][0]);
      acc[2][1] = fmaf(a.z, w.y, acc[2][1]);
      acc[3][0] = fmaf(a.w, w.x, acc[3][0]);
      acc[3][1] = fmaf(a.w, w.y, acc[3][1]);
    }
    if (kt + 1 < 16) {
      float* Asn = AsG + (cb ^ 1) * 1024;
      float* Wsn = WsG + (cb ^ 1) * 1152;
      float a[8]; unpack8(pa, a);
#pragma unroll
      for (int i = 0; i < 8; ++i) Asn[(ac + i) * 32 + ar] = a[i];
      Wsn[(wk+0)*36+wr] = pw0.x; Wsn[(wk+1)*36+wr] = pw0.y;
      Wsn[(wk+2)*36+wr] = pw0.z; Wsn[(wk+3)*36+wr] = pw0.w;
      Wsn[(wk+4)*36+wr] = pw1.x; Wsn[(wk+5)*36+wr] = pw1.y;
      Wsn[(wk+6)*36+wr] = pw1.z; Wsn[(wk+7)*36+wr] = pw1.w;
    }
    if (kt + 2 < 16) { pa = na; pw0 = nw0; pw1 = nw1; }
    __syncthreads();
    cb ^= 1;
  }
}

// ---- L0 GEMM: tile 32b x 64o, K=512 whole, 256 thr, micro 4x2.
// As 2buf x [32k][32b]; Ws 2buf x [32k][68].
__device__ __forceinline__ void gemm_x64(
    const float* __restrict__ xrow,   // x + t*512, row stride NT*512
    const float* __restrict__ W,      // [o][512]
    int bBase, int oBase, int tid,
    float* As, float* Ws, float acc[4][2])
{
  const int ar = tid >> 3, ac4 = (tid & 7) << 2;
  const int wr = tid >> 2, wk = (tid & 3) << 3;
  const int tb4 = (tid >> 5) << 2;
  const int to2 = (tid & 31) << 1;
  const float* Af = xrow + (size_t)(bBase + ar) * (NT * 512) + ac4;
  const float* Wr = W + (size_t)(oBase + wr) * 512 + wk;

  {
    float4 a = *(const float4*)Af;
    float4 w0 = *(const float4*)Wr;
    float4 w1 = *(const float4*)(Wr + 4);
    As[(ac4+0)*32+ar] = a.x; As[(ac4+1)*32+ar] = a.y;
    As[(ac4+2)*32+ar] = a.z; As[(ac4+3)*32+ar] = a.w;
    Ws[(wk+0)*68+wr] = w0.x; Ws[(wk+1)*68+wr] = w0.y;
    Ws[(wk+2)*68+wr] = w0.z; Ws[(wk+3)*68+wr] = w0.w;
    Ws[(wk+4)*68+wr] = w1.x; Ws[(wk+5)*68+wr] = w1.y;
    Ws[(wk+6)*68+wr] = w1.z; Ws[(wk+7)*68+wr] = w1.w;
  }
  float4 paf = *(const float4*)(Af + 32);
  float4 pw0 = *(const float4*)(Wr + 32);
  float4 pw1 = *(const float4*)(Wr + 36);
  __syncthreads();

  int cb = 0;
#pragma unroll 1
  for (int kt = 0; kt < 16; ++kt) {
    float4 naf, nw0, nw1;
    if (kt + 2 < 16) {
      const int ko = (kt + 2) << 5;
      naf = *(const float4*)(Af + ko);
      nw0 = *(const float4*)(Wr + ko);
      nw1 = *(const float4*)(Wr + ko + 4);
    }
    const float* Asb = As + cb * 1024;
    const float* Wsb = Ws + cb * 2176;
#pragma unroll
    for (int k = 0; k < 32; ++k) {
      const float4 a = *(const float4*)&Asb[k * 32 + tb4];
      const float2 w = *(const float2*)&Wsb[k * 68 + to2];
      acc[0][0] = fmaf(a.x, w.x, acc[0][0]);
      acc[0][1] = fmaf(a.x, w.y, acc[0][1]);
      acc[1][0] = fmaf(a.y, w.x, acc[1][0]);
      acc[1][1] = fmaf(a.y, w.y, acc[1][1]);
      acc[2][0] = fmaf(a.z, w.x, acc[2][0]);
      acc[2][1] = fmaf(a.z, w.y, acc[2][1]);
      acc[3][0] = fmaf(a.w, w.x, acc[3][0]);
      acc[3][1] = fmaf(a.w, w.y, acc[3][1]);
    }
    if (kt + 1 < 16) {
      float* Asn = As + (cb ^ 1) * 1024;
      float* Wsn = Ws + (cb ^ 1) * 2176;
      Asn[(ac4+0)*32+ar] = paf.x; Asn[(ac4+1)*32+ar] = paf.y;
      Asn[(ac4+2)*32+ar] = paf.z; Asn[(ac4+3)*32+ar] = paf.w;
      Wsn[(wk+0)*68+wr] = pw0.x; Wsn[(wk+1)*68+wr] = pw0.y;
      Wsn[(wk+2)*68+wr] = pw0.z; Wsn[(wk+3)*68+wr] = pw0.w;
      Wsn[(wk+4)*68+wr] = pw1.x; Wsn[(wk+5)*68+wr] = pw1.y;
      Wsn[(wk+6)*68+wr] = pw1.z; Wsn[(wk+7)*68+wr] = pw1.w;
    }
    if (kt + 2 < 16) { paf = naf; pw0 = nw0; pw1 = nw1; }
    __syncthreads();
    cb ^= 1;
  }
}

// ---- one phase for one block; 512-block layout.
// g0 [0,64): L0 (t=p) + L4 piggyback (t=p-5). g1 [64,192): L1 (p-1).
// g2 [192,320): 2a (p-2). g3 [320,448): 2b (p-3). g4 [448,512): L3 (p-4).
template<bool PERSIST>
__device__ __forceinline__ void do_phase512(
    int g, int lb, int p,
    const float* __restrict__ x,
    const float* __restrict__ W0, const float* __restrict__ W1,
    const float* __restrict__ W2a, const float* __restrict__ W2b,
    const float* __restrict__ W3, const float* __restrict__ W4,
    float* __restrict__ wf, float* __restrict__ out,
    float* AsB, float* WsB, float* vpriv)
{
  unsigned char* sb = (unsigned char*)(wf + OFF_BYTE);
  float* c2a = wf + OFF_C2A;
  const int cur = p & 1, prev = cur ^ 1;
  const int tid = threadIdx.x;

  if (g == 0) {
    const int t0 = p;
    if (t0 < NT) {
      const int bBase = (lb >> 4) << 5;
      const int oBase = (lb & 15) << 6;
      float acc[4][2] = {{0.f,0.f},{0.f,0.f},{0.f,0.f},{0.f,0.f}};
      gemm_x64(x + (size_t)t0 * 512, W0, bBase, oBase, tid, AsB, WsB, acc);
      const int tb4 = (tid >> 5) << 2, to2 = (tid & 31) << 1;
      unsigned char* sOut = sb + BS0 + (size_t)cur * 131072;
      float* vg = wf + OFF_V0;
#pragma unroll
      for (int i = 0; i < 4; ++i) {
        const int b = bBase + tb4 + i;
        int si[2];
#pragma unroll
        for (int j = 0; j < 2; ++j) {
          const int o = oBase + to2 + j;
          float vold = PERSIST ? vpriv[i*2+j] : vg[(size_t)b*1024 + o];
          float vv = __fadd_rn(__fmul_rn(0.90f, vold), acc[i][j]);
          int s = (vv >= 0.5f) ? 1 : 0;
          float sf = (float)s;
          float nv = __fmul_rn(vv, __fsub_rn(1.0f, sf));
          if (PERSIST) vpriv[i*2+j] = nv; else vg[(size_t)b*1024 + o] = nv;
          si[j] = s;
        }
        st_u16_agent(sOut + (size_t)b * 1024 + oBase + to2,
                     (unsigned short)(si[0] | (si[1] << 8)));
      }
    }
    const int t4 = p - 5;
    if (t4 >= 0 && t4 < NT) {
      const int b4 = ((lb >> 4) << 5) + (tid >> 3);
      const int o4 = ((lb & 15) << 3) + (tid & 7);
      const unsigned char* a3 = sb + BS3 + (size_t)prev * 65536 + (size_t)b4 * 512;
      const float* w4r = W4 + (size_t)o4 * 512;
      float acc = 0.f;
#pragma unroll 4
      for (int kk = 0; kk < 512; kk += 8) {
        float a[8]; unpack8(ld_u64_agent(a3 + kk), a);
        float4 wA = *(const float4*)(w4r + kk);
        float4 wB = *(const float4*)(w4r + kk + 4);
        acc = fmaf(a[0], wA.x, acc);
        acc = fmaf(a[1], wA.y, acc);
        acc = fmaf(a[2], wA.z, acc);
        acc = fmaf(a[3], wA.w, acc);
        acc = fmaf(a[4], wB.x, acc);
        acc = fmaf(a[5], wB.y, acc);
        acc = fmaf(a[6], wB.z, acc);
        acc = fmaf(a[7], wB.w, acc);
      }
      float vold = PERSIST ? vpriv[8] : wf[OFF_VO + b4 * 128 + o4];
      float vv = __fadd_rn(__fmul_rn(0.82f, vold), acc);
      int s = (vv >= 0.8f) ? 1 : 0;
      float sf = (float)s;
      float nv = __fmul_rn(vv, __fsub_rn(1.0f, sf));
      if (PERSIST) vpriv[8] = nv; else wf[OFF_VO + b4 * 128 + o4] = nv;
      out[(size_t)b4 * (NT * 128) + (size_t)t4 * 128 + o4] = sf;
      if (PERSIST) vpriv[9] = __fadd_rn(vpriv[9], sf);
      else wf[OFF_CNT + b4 * 128 + o4] = __fadd_rn(wf[OFF_CNT + b4 * 128 + o4], sf);
    }
    return;
  }

  const int dt = (g == 1) ? 1 : (g == 2) ? 2 : (g == 3) ? 3 : 4;
  const int t = p - dt;
  if (t < 0 || t >= NT) return;

  const unsigned char* Ab; const float* Wm;
  switch (g) {
    case 1:  Ab = sb + BS0 + (size_t)prev * 131072; Wm = W1;  break;
    case 2:  Ab = sb + BS1 + (size_t)prev * 131072; Wm = W2a; break;
    case 3:  Ab = sb + BS2 + (size_t)prev * 131072; Wm = W2b; break;
    default: Ab = sb + BS2 + (size_t)prev * 131072; Wm = W3;  break;
  }
  const int ntO = (g == 4) ? 16 : 32;
  const int N   = (g == 4) ? 512 : 1024;
  const int bBase = (lb / ntO) << 5;
  const int oBase = (lb % ntO) << 5;
  const int grp = tid >> 7, lt = tid & 127;

  float acc[4][2] = {{0.f,0.f},{0.f,0.f},{0.f,0.f},{0.f,0.f}};
  gemm_split32(Ab, Wm, bBase, oBase, grp, lt,
               AsB + grp * 2048, WsB + grp * 2304, acc);

  // fold panels (BLAS order: result = fadd(panLow, panHigh))
  float* foldp = AsB + 2048;  // group-1 As region, reads all done
  if (grp == 1) {
    float4 h0, h1;
    h0.x = acc[0][0]; h0.y = acc[0][1]; h0.z = acc[1][0]; h0.w = acc[1][1];
    h1.x = acc[2][0]; h1.y = acc[2][1]; h1.z = acc[3][0]; h1.w = acc[3][1];
    *(float4*)(foldp + lt * 8) = h0;
    *(float4*)(foldp + lt * 8 + 4) = h1;
  }
  __syncthreads();
  if (grp == 0) {
    float4 h0 = *(const float4*)(foldp + lt * 8);
    float4 h1 = *(const float4*)(foldp + lt * 8 + 4);
    acc[0][0] = __fadd_rn(acc[0][0], h0.x); acc[0][1] = __fadd_rn(acc[0][1], h0.y);
    acc[1][0] = __fadd_rn(acc[1][0], h0.z); acc[1][1] = __fadd_rn(acc[1][1], h0.w);
    acc[2][0] = __fadd_rn(acc[2][0], h1.x); acc[2][1] = __fadd_rn(acc[2][1], h1.y);
    acc[3][0] = __fadd_rn(acc[3][0], h1.z); acc[3][1] = __fadd_rn(acc[3][1], h1.w);

    const int tb4 = (lt >> 4) << 2, to2 = (lt & 15) << 1;
    if (g == 2) {
      float* dst = c2a + (size_t)cur * 131072;
#pragma unroll
      for (int i = 0; i < 4; ++i) {
        const int b = bBase + tb4 + i;
        F2U u; u.f.x = acc[i][0]; u.f.y = acc[i][1];
        st_u64_agent(dst + (size_t)b * 1024 + oBase + to2, u.u);
      }
    } else {
      float alpha; float* vg; unsigned char* sOut;
      if (g == 1)      { alpha = 0.95f; vg = wf + OFF_V1; sOut = sb + BS1 + (size_t)cur * 131072; }
      else if (g == 3) { alpha = 0.93f; vg = wf + OFF_V2; sOut = sb + BS2 + (size_t)cur * 131072; }
      else             { alpha = 0.90f; vg = wf + OFF_V3; sOut = sb + BS3 + (size_t)cur * 65536;  }
      const float* c2aPrev = c2a + (size_t)prev * 131072;
#pragma unroll
      for (int i = 0; i < 4; ++i) {
        const int b = bBase + tb4 + i;
        float cin[2];
        if (g == 3) {
          F2U u; u.u = ld_u64_agentf(c2aPrev + (size_t)b * 1024 + oBase + to2);
          // reference: ONE __fadd_rn combining the two matmuls, W2a first
          cin[0] = __fadd_rn(u.f.x, acc[i][0]);
          cin[1] = __fadd_rn(u.f.y, acc[i][1]);
        } else {
          cin[0] = acc[i][0]; cin[1] = acc[i][1];
        }
        int si[2];
#pragma unroll
        for (int j = 0; j < 2; ++j) {
          const int o = oBase + to2 + j;
          float vold = PERSIST ? vpriv[i*2+j] : vg[(size_t)b * N + o];
          float vv = __fadd_rn(__fmul_rn(alpha, vold), cin[j]);
          int s = (vv >= 0.5f) ? 1 : 0;
          float sf = (float)s;
          float nv = __fmul_rn(vv, __fsub_rn(1.0f, sf));
          if (PERSIST) vpriv[i*2+j] = nv; else vg[(size_t)b * N + o] = nv;
          si[j] = s;
        }
        st_u16_agent(sOut + (size_t)b * N + oBase + to2,
                     (unsigned short)(si[0] | (si[1] << 8)));
      }
    }
  }
}

// ---- fence-free phase barrier ----
__device__ __forceinline__ void phase_barrier(int p, unsigned* arr, unsigned* flag) {
  const int tid = threadIdx.x;
  __syncthreads();  // drains all waves' vmem (sc1 stores now at IF)
  const unsigned tgt = (unsigned)(p + 1);
  if (blockIdx.x == 0) {
    if (tid == 0) st_u32_agent(arr, tgt);
    int ok;
    do {
      unsigned a0 = ld_u32_agent(arr + (tid * 2) * 16);
      unsigned a1 = ld_u32_agent(arr + (tid * 2 + 1) * 16);
      ok = __syncthreads_and((int)(a0 >= tgt && a1 >= tgt));
      if (!ok) __builtin_amdgcn_s_sleep(1);
    } while (!ok);
    if (tid == 0) st_u32_agent(flag, tgt);
    __syncthreads();
  } else {
    if (tid == 0) {
      st_u32_agent(arr + blockIdx.x * 16, tgt);
      while (ld_u32_agent(flag) < tgt) __builtin_amdgcn_s_sleep(2);
    }
    __syncthreads();
  }
}

__global__ __launch_bounds__(256) void pre_kernel(float* __restrict__ wf) {
  size_t i = (size_t)blockIdx.x * blockDim.x + threadIdx.x;
  size_t stride = (size_t)gridDim.x * blockDim.x;
  for (size_t j = i; j < WS_TOTAL; j += stride) wf[j] = 0.0f;
}

// ---- persistent fence-free kernel ----
__global__ __launch_bounds__(256, 2) void persist3(
    const float* __restrict__ x,
    const float* __restrict__ W0, const float* __restrict__ W1,
    const float* __restrict__ W2a, const float* __restrict__ W2b,
    const float* __restrict__ W3, const float* __restrict__ W4,
    float* __restrict__ wf, float* __restrict__ out)
{
  __shared__ float AsB[4096];       // 16 KB (2 groups x 2 buf x 1024)
  __shared__ float WsB[4608];       // 18.4 KB
  __shared__ float vLds[256][11];   // 11.3 KB per-thread v/cnt state
  const int tid = threadIdx.x;
  float* vpriv = &vLds[tid][0];
#pragma unroll
  for (int i = 0; i < 11; ++i) vpriv[i] = 0.0f;

  unsigned* arr  = (unsigned*)(wf + OFF_ARR);
  unsigned* flag = (unsigned*)(wf + OFF_FLAGF);

  const int blk = blockIdx.x;
  int g, lb;
  if (blk < 64)       { g = 0; lb = blk; }
  else if (blk < 192) { g = 1; lb = blk - 64; }
  else if (blk < 320) { g = 2; lb = blk - 192; }
  else if (blk < 448) { g = 3; lb = blk - 320; }
  else                { g = 4; lb = blk - 448; }

  for (int p = 0; p < NT + 5; ++p) {
    do_phase512<true>(g, lb, p, x, W0, W1, W2a, W2b, W3, W4, wf, out,
                      AsB, WsB, vpriv);
    phase_barrier(p, arr, flag);
  }

  if (g == 0) {  // counts epilogue (plain stores, flushed at kernel end)
    const int b4 = ((lb >> 4) << 5) + (tid >> 3);
    const int o4 = ((lb & 15) << 3) + (tid & 7);
    out[(size_t)128 * NT * 128 + (size_t)b4 * 128 + o4] = vpriv[9];
  }
}

// ---------------------------------------------------------------------------
// ------------------------ FALLBACK: multi-launch ---------------------------
// ---------------------------------------------------------------------------

__global__ __launch_bounds__(256) void init_kernel(float* __restrict__ wf) {
  size_t i = (size_t)blockIdx.x * blockDim.x + threadIdx.x;
  size_t stride = (size_t)gridDim.x * blockDim.x;
  for (size_t j = i; j < WS_TOTAL; j += stride) wf[j] = 0.0f;
}

__global__ __launch_bounds__(256) void phase_kernel512(
    const float* __restrict__ x,
    const float* __restrict__ W0, const float* __restrict__ W1,
    const float* __restrict__ W2a, const float* __restrict__ W2b,
    const float* __restrict__ W3, const float* __restrict__ W4,
    float* __restrict__ wf, float* __restrict__ out, int p)
{
  __shared__ float AsB[4096];
  __shared__ float WsB[4608];
  const int blk = blockIdx.x;
  int g, lb;
  if (blk < 64)       { g = 0; lb = blk; }
  else if (blk < 192) { g = 1; lb = blk - 64; }
  else if (blk < 320) { g = 2; lb = blk - 192; }
  else if (blk < 448) { g = 3; lb = blk - 320; }
  else                { g = 4; lb = blk - 448; }
  float vd[11];
  do_phase512<false>(g, lb, p, x, W0, W1, W2a, W2b, W3, W4, wf, out,
                     AsB, WsB, vd);
}

__global__ __launch_bounds__(256) void fin_kernel(const float* __restrict__ counts,
                                                  float* __restrict__ out) {
  int i = blockIdx.x * blockDim.x + threadIdx.x;
  if (i < 128 * 128) out[(size_t)128 * NT * 128 + i] = counts[i];
}

// ---------------------------------------------------------------------------
// -------------------------------- launcher ---------------------------------
// ---------------------------------------------------------------------------

extern "C" void kernel_launch(void* const* d_in, const int* in_sizes, int n_in,
                              void* d_out, int out_size, void* d_ws, size_t ws_size,
                              hipStream_t stream) {
  const float* x   = (const float*)d_in[0];
  const float* W0  = (const float*)d_in[1];
  const float* W1  = (const float*)d_in[2];
  const float* W2a = (const float*)d_in[3];
  const float* W2b = (const float*)d_in[4];
  const float* W3  = (const float*)d_in[5];
  const float* W4  = (const float*)d_in[6];
  float* wf  = (float*)d_ws;
  float* out = (float*)d_out;

  int maxBlocksPerCU = 0;
  hipError_t qe = hipOccupancyMaxActiveBlocksPerMultiprocessor(
      &maxBlocksPerCU, persist3, 256, 0);
  const bool wsOK = ws_size >= WS_TOTAL * sizeof(float);

  if (qe == hipSuccess && maxBlocksPerCU >= 2 && wsOK) {
    pre_kernel<<<256, 256, 0, stream>>>(wf);
    persist3<<<NBLK, 256, 0, stream>>>(x, W0, W1, W2a, W2b, W3, W4, wf, out);
  } else {
    (void)hipGetLastError();
    init_kernel<<<512, 256, 0, stream>>>(wf);
    for (int p = 0; p < NT + 5; ++p) {
      phase_kernel512<<<NBLK, 256, 0, stream>>>(x, W0, W1, W2a, W2b, W3, W4,
                                                wf, out, p);
    }
    fin_kernel<<<64, 256, 0, stream>>>(wf + OFF_CNT, out);
  }
}

// Round 8
// 19602.856 us; speedup vs baseline: 3.9499x; 1.0023x over previous
//
#include <hip/hip_runtime.h>
#include <cstddef>

// SafetyReflexSNN: 5-layer LIF SNN, B=128, T=512.
//
// ROUND 19: SELF-TIMED DATAFLOW PIPELINE (no global barrier).
// Round-18 (19.6 ms): fence-free transport proved out (WRITE 91 GB -> 0.5 MB)
// but 38 us/phase vs ~10 us VALU floor = stall-bound: (1) g0's L4 piggyback
// did 64 serial sc1 loads (~6 us straggler) and (2) the global barrier
// convoyed all 512 blocks behind the slowest. This round:
//  - Per-stage completion counters C[0..4] (relaxed agent atomics). Stage g
//    at phase p polls ONLY its deps: producers' C >= nblk*p (data ready) and
//    consumers' C >= nblk*p (parity buffer free). +-1 phase slack absorbs
//    stragglers. Increment after __syncthreads (vmcnt drained -> sc1 stores
//    at IF) — same visibility contract as the proven round-18 barrier.
//  - L4: s3 tile (32 rows x 512 B) cooperatively staged into LDS (WsB
//    scratch, rows padded to 65 u64 -> no bank conflicts) via 8 coalesced
//    sc1 loads/thread; FMA from LDS in identical ascending-k order.
//
// Dependency audit (writes buf[p&1], read by consumer at p+1; prior reader
// at p-1): g0 waits C1>=128p (s0 anti), C4>=64p (s3 ready for L4);
// g1 waits C0>=64p (s0), C2>=128p (s1 anti); g2 waits C1>=128p (s1),
// C3>=128p (c2a anti); g3 waits C2>=128p (c2a), C3>=128p (s2 recurrent),
// C4>=64p (s2 anti vs L3 read); g4 waits C3>=128p (s2), C0>=64p (s3 anti).
//
// NUMERICS (absmax 0.0 inherited): identical op sequences: ascending-k
// fmaf chain per panel; K=1024 folds with one __fadd_rn(low, high);
// layer-2 combine = one __fadd_rn(W2a_res, W2b_res); LIF = __fmul_rn /
// __fadd_rn / __fsub_rn; counts in ascending t.

#define NB 128
#define NT 512
#define NBLK 512

// ---- workspace layout (floats) ----
enum : size_t {
  OFF_V0   = 0,                       // fallback-only state
  OFF_V1   = OFF_V0 + 131072,
  OFF_V2   = OFF_V1 + 131072,
  OFF_V3   = OFF_V2 + 131072,
  OFF_VO   = OFF_V3 + 65536,
  OFF_CNT  = OFF_VO + 16384,
  OFF_C2A  = OFF_CNT + 16384,         // 2 x [128][1024] float
  OFF_BYTE = OFF_C2A + 262144,        // byte region (float idx)
  WS_FLOATS = OFF_BYTE + 229376,      // 983040 floats
  OFF_ARR  = WS_FLOATS,               // u32 stage counters (64B spacing)
  WS_TOTAL = OFF_ARR + 512
};
#define BS0 0
#define BS1 262144
#define BS2 524288
#define BS3 786432

// ---- agent-scope (sc1) relaxed transport helpers ----
__device__ __forceinline__ void st_u16_agent(unsigned char* p, unsigned short v) {
  __hip_atomic_store((unsigned short*)p, v, __ATOMIC_RELAXED, __HIP_MEMORY_SCOPE_AGENT);
}
__device__ __forceinline__ unsigned long long ld_u64_agent(const unsigned char* p) {
  return __hip_atomic_load((const unsigned long long*)p, __ATOMIC_RELAXED, __HIP_MEMORY_SCOPE_AGENT);
}
__device__ __forceinline__ void st_u64_agent(void* p, unsigned long long v) {
  __hip_atomic_store((unsigned long long*)p, v, __ATOMIC_RELAXED, __HIP_MEMORY_SCOPE_AGENT);
}
__device__ __forceinline__ unsigned long long ld_u64_agentf(const float* p) {
  return __hip_atomic_load((const unsigned long long*)p, __ATOMIC_RELAXED, __HIP_MEMORY_SCOPE_AGENT);
}
__device__ __forceinline__ unsigned ld_u32_agent(const unsigned* p) {
  return __hip_atomic_load(p, __ATOMIC_RELAXED, __HIP_MEMORY_SCOPE_AGENT);
}

union F2U { float2 f; unsigned long long u; };

__device__ __forceinline__ void unpack8(unsigned long long v, float* f) {
  unsigned lo = (unsigned)v, hi = (unsigned)(v >> 32);
  f[0] = (float)(lo & 0xff); f[1] = (float)((lo >> 8) & 0xff);
  f[2] = (float)((lo >> 16) & 0xff); f[3] = (float)(lo >> 24);
  f[4] = (float)(hi & 0xff); f[5] = (float)((hi >> 8) & 0xff);
  f[6] = (float)((hi >> 16) & 0xff); f[7] = (float)(hi >> 24);
}

// ---- split GEMM: tile 32b x 32o, K=1024 in 2 wave-group panels of 512. ----
__device__ __forceinline__ void gemm_split32(
    const unsigned char* __restrict__ Abase,  // byte spikes, row stride 1024
    const float* __restrict__ W,              // [o][1024]
    int bBase, int oBase, int grp, int lt,
    float* AsG, float* WsG, float acc[4][2])
{
  const int ar = lt >> 2, ac = (lt & 3) << 3;   // A: row ar, 8 k-bytes
  const int wr = lt >> 2, wk = (lt & 3) << 3;   // W: o-row wr, 8 k
  const int tb4 = (lt >> 4) << 2;               // compute: 4 b
  const int to2 = (lt & 15) << 1;               // compute: 2 o
  const int kb = grp << 9;

  const unsigned char* Arow = Abase + (size_t)(bBase + ar) * 1024 + kb + ac;
  const float* Wr = W + (size_t)(oBase + wr) * 1024 + kb + wk;

  {  // stage k-tile 0 -> buf 0
    float a[8]; unpack8(ld_u64_agent(Arow), a);
    float4 w0 = *(const float4*)(Wr);
    float4 w1 = *(const float4*)(Wr + 4);
#pragma unroll
    for (int i = 0; i < 8; ++i) AsG[(ac + i) * 32 + ar] = a[i];
    WsG[(wk+0)*36+wr] = w0.x; WsG[(wk+1)*36+wr] = w0.y;
    WsG[(wk+2)*36+wr] = w0.z; WsG[(wk+3)*36+wr] = w0.w;
    WsG[(wk+4)*36+wr] = w1.x; WsG[(wk+5)*36+wr] = w1.y;
    WsG[(wk+6)*36+wr] = w1.z; WsG[(wk+7)*36+wr] = w1.w;
  }
  unsigned long long pa = ld_u64_agent(Arow + 32);
  float4 pw0 = *(const float4*)(Wr + 32);
  float4 pw1 = *(const float4*)(Wr + 36);
  __syncthreads();

  int cb = 0;
#pragma unroll 1
  for (int kt = 0; kt < 16; ++kt) {
    unsigned long long na; float4 nw0, nw1;
    if (kt + 2 < 16) {  // 2-deep prefetch
      const int ko = (kt + 2) << 5;
      na  = ld_u64_agent(Arow + ko);
      nw0 = *(const float4*)(Wr + ko);
      nw1 = *(const float4*)(Wr + ko + 4);
    }
    const float* Asb = AsG + cb * 1024;
    const float* Wsb = WsG + cb * 1152;
#pragma unroll
    for (int k = 0; k < 32; ++k) {
      const float4 a = *(const float4*)&Asb[k * 32 + tb4];
      const float2 w = *(const float2*)&Wsb[k * 36 + to2];
      acc[0][0] = fmaf(a.x, w.x, acc[0][0]);
      acc[0][1] = fmaf(a.x, w.y, acc[0][1]);
      acc[1][0] = fmaf(a.y, w.x, acc[1][0]);
      acc[1][1] = fmaf(a.y, w.y, acc[1][1]);
      acc[2][0] = fmaf(a.z, w.x, acc[2][0]);
      acc[2][1] = fmaf(a.z, w.y, acc[2][1]);
      acc[3][0] = fmaf(a.w, w.x, acc[3][0]);
      acc[3][1] = fmaf(a.w, w.y, acc[3][1]);
    }
    if (kt + 1 < 16) {
      float* Asn = AsG + (cb ^ 1) * 1024;
      float* Wsn = WsG + (cb ^ 1) * 1152;
      float a[8]; unpack8(pa, a);
#pragma unroll
      for (int i = 0; i < 8; ++i) Asn[(ac + i) * 32 + ar] = a[i];
      Wsn[(wk+0)*36+wr] = pw0.x; Wsn[(wk+1)*36+wr] = pw0.y;
      Wsn[(wk+2)*36+wr] = pw0.z; Wsn[(wk+3)*36+wr] = pw0.w;
      Wsn[(wk+4)*36+wr] = pw1.x; Wsn[(wk+5)*36+wr] = pw1.y;
      Wsn[(wk+6)*36+wr] = pw1.z; Wsn[(wk+7)*36+wr] = pw1.w;
    }
    if (kt + 2 < 16) { pa = na; pw0 = nw0; pw1 = nw1; }
    __syncthreads();
    cb ^= 1;
  }
}

// ---- L0 GEMM: tile 32b x 64o, K=512 whole, 256 thr, micro 4x2. ----
__device__ __forceinline__ void gemm_x64(
    const float* __restrict__ xrow,   // x + t*512, row stride NT*512
    const float* __restrict__ W,      // [o][512]
    int bBase, int oBase, int tid,
    float* As, float* Ws, float acc[4][2])
{
  const int ar = tid >> 3, ac4 = (tid & 7) << 2;
  const int wr = tid >> 2, wk = (tid & 3) << 3;
  const int tb4 = (tid >> 5) << 2;
  const int to2 = (tid & 31) << 1;
  const float* Af = xrow + (size_t)(bBase + ar) * (NT * 512) + ac4;
  const float* Wr = W + (size_t)(oBase + wr) * 512 + wk;

  {
    float4 a = *(const float4*)Af;
    float4 w0 = *(const float4*)Wr;
    float4 w1 = *(const float4*)(Wr + 4);
    As[(ac4+0)*32+ar] = a.x; As[(ac4+1)*32+ar] = a.y;
    As[(ac4+2)*32+ar] = a.z; As[(ac4+3)*32+ar] = a.w;
    Ws[(wk+0)*68+wr] = w0.x; Ws[(wk+1)*68+wr] = w0.y;
    Ws[(wk+2)*68+wr] = w0.z; Ws[(wk+3)*68+wr] = w0.w;
    Ws[(wk+4)*68+wr] = w1.x; Ws[(wk+5)*68+wr] = w1.y;
    Ws[(wk+6)*68+wr] = w1.z; Ws[(wk+7)*68+wr] = w1.w;
  }
  float4 paf = *(const float4*)(Af + 32);
  float4 pw0 = *(const float4*)(Wr + 32);
  float4 pw1 = *(const float4*)(Wr + 36);
  __syncthreads();

  int cb = 0;
#pragma unroll 1
  for (int kt = 0; kt < 16; ++kt) {
    float4 naf, nw0, nw1;
    if (kt + 2 < 16) {
      const int ko = (kt + 2) << 5;
      naf = *(const float4*)(Af + ko);
      nw0 = *(const float4*)(Wr + ko);
      nw1 = *(const float4*)(Wr + ko + 4);
    }
    const float* Asb = As + cb * 1024;
    const float* Wsb = Ws + cb * 2176;
#pragma unroll
    for (int k = 0; k < 32; ++k) {
      const float4 a = *(const float4*)&Asb[k * 32 + tb4];
      const float2 w = *(const float2*)&Wsb[k * 68 + to2];
      acc[0][0] = fmaf(a.x, w.x, acc[0][0]);
      acc[0][1] = fmaf(a.x, w.y, acc[0][1]);
      acc[1][0] = fmaf(a.y, w.x, acc[1][0]);
      acc[1][1] = fmaf(a.y, w.y, acc[1][1]);
      acc[2][0] = fmaf(a.z, w.x, acc[2][0]);
      acc[2][1] = fmaf(a.z, w.y, acc[2][1]);
      acc[3][0] = fmaf(a.w, w.x, acc[3][0]);
      acc[3][1] = fmaf(a.w, w.y, acc[3][1]);
    }
    if (kt + 1 < 16) {
      float* Asn = As + (cb ^ 1) * 1024;
      float* Wsn = Ws + (cb ^ 1) * 2176;
      Asn[(ac4+0)*32+ar] = paf.x; Asn[(ac4+1)*32+ar] = paf.y;
      Asn[(ac4+2)*32+ar] = paf.z; Asn[(ac4+3)*32+ar] = paf.w;
      Wsn[(wk+0)*68+wr] = pw0.x; Wsn[(wk+1)*68+wr] = pw0.y;
      Wsn[(wk+2)*68+wr] = pw0.z; Wsn[(wk+3)*68+wr] = pw0.w;
      Wsn[(wk+4)*68+wr] = pw1.x; Wsn[(wk+5)*68+wr] = pw1.y;
      Wsn[(wk+6)*68+wr] = pw1.z; Wsn[(wk+7)*68+wr] = pw1.w;
    }
    if (kt + 2 < 16) { paf = naf; pw0 = nw0; pw1 = nw1; }
    __syncthreads();
    cb ^= 1;
  }
}

// ---- one phase for one block; 512-block layout.
// g0 [0,64): L0 (t=p) + L4 (t=p-5, LDS-staged). g1 [64,192): L1 (p-1).
// g2 [192,320): 2a (p-2). g3 [320,448): 2b (p-3). g4 [448,512): L3 (p-4).
template<bool PERSIST>
__device__ __forceinline__ void do_phase512(
    int g, int lb, int p,
    const float* __restrict__ x,
    const float* __restrict__ W0, const float* __restrict__ W1,
    const float* __restrict__ W2a, const float* __restrict__ W2b,
    const float* __restrict__ W3, const float* __restrict__ W4,
    float* __restrict__ wf, float* __restrict__ out,
    float* AsB, float* WsB, float* vpriv)
{
  unsigned char* sb = (unsigned char*)(wf + OFF_BYTE);
  float* c2a = wf + OFF_C2A;
  const int cur = p & 1, prev = cur ^ 1;
  const int tid = threadIdx.x;

  if (g == 0) {
    const int t0 = p;
    if (t0 < NT) {
      const int bBase = (lb >> 4) << 5;
      const int oBase = (lb & 15) << 6;
      float acc[4][2] = {{0.f,0.f},{0.f,0.f},{0.f,0.f},{0.f,0.f}};
      gemm_x64(x + (size_t)t0 * 512, W0, bBase, oBase, tid, AsB, WsB, acc);
      const int tb4 = (tid >> 5) << 2, to2 = (tid & 31) << 1;
      unsigned char* sOut = sb + BS0 + (size_t)cur * 131072;
      float* vg = wf + OFF_V0;
#pragma unroll
      for (int i = 0; i < 4; ++i) {
        const int b = bBase + tb4 + i;
        int si[2];
#pragma unroll
        for (int j = 0; j < 2; ++j) {
          const int o = oBase + to2 + j;
          float vold = PERSIST ? vpriv[i*2+j] : vg[(size_t)b*1024 + o];
          float vv = __fadd_rn(__fmul_rn(0.90f, vold), acc[i][j]);
          int s = (vv >= 0.5f) ? 1 : 0;
          float sf = (float)s;
          float nv = __fmul_rn(vv, __fsub_rn(1.0f, sf));
          if (PERSIST) vpriv[i*2+j] = nv; else vg[(size_t)b*1024 + o] = nv;
          si[j] = s;
        }
        st_u16_agent(sOut + (size_t)b * 1024 + oBase + to2,
                     (unsigned short)(si[0] | (si[1] << 8)));
      }
    }
    const int t4 = p - 5;
    if (t4 >= 0 && t4 < NT) {
      const int bBase = (lb >> 4) << 5;
      const int b4 = bBase + (tid >> 3);
      const int o4 = ((lb & 15) << 3) + (tid & 7);
      // cooperative stage: s3 tile rows [bBase, bBase+32) x 512 B into LDS.
      // WsB scratch (4608 f = 2304 u64 >= 32*65=2080), row stride 65 u64
      // (pad kills the 512B-stride bank conflict). gemm_x64's last
      // __syncthreads guarantees WsB reads are done.
      unsigned long long* s3l = (unsigned long long*)WsB;
      const unsigned char* s3g = sb + BS3 + (size_t)prev * 65536 + (size_t)bBase * 512;
#pragma unroll
      for (int i = 0; i < 8; ++i) {
        const int idx = tid + (i << 8);        // u64 index in 32x64 tile
        const int r = idx >> 6, c = idx & 63;
        s3l[r * 65 + c] = ld_u64_agent(s3g + (size_t)idx * 8);
      }
      __syncthreads();
      const unsigned long long* row = s3l + (size_t)(tid >> 3) * 65;
      const float* w4r = W4 + (size_t)o4 * 512;
      float acc = 0.f;
#pragma unroll 8
      for (int kk = 0; kk < 512; kk += 8) {
        float a[8]; unpack8(row[kk >> 3], a);
        float4 wA = *(const float4*)(w4r + kk);
        float4 wB = *(const float4*)(w4r + kk + 4);
        acc = fmaf(a[0], wA.x, acc);
        acc = fmaf(a[1], wA.y, acc);
        acc = fmaf(a[2], wA.z, acc);
        acc = fmaf(a[3], wA.w, acc);
        acc = fmaf(a[4], wB.x, acc);
        acc = fmaf(a[5], wB.y, acc);
        acc = fmaf(a[6], wB.z, acc);
        acc = fmaf(a[7], wB.w, acc);
      }
      float vold = PERSIST ? vpriv[8] : wf[OFF_VO + b4 * 128 + o4];
      float vv = __fadd_rn(__fmul_rn(0.82f, vold), acc);
      int s = (vv >= 0.8f) ? 1 : 0;
      float sf = (float)s;
      float nv = __fmul_rn(vv, __fsub_rn(1.0f, sf));
      if (PERSIST) vpriv[8] = nv; else wf[OFF_VO + b4 * 128 + o4] = nv;
      out[(size_t)b4 * (NT * 128) + (size_t)t4 * 128 + o4] = sf;
      if (PERSIST) vpriv[9] = __fadd_rn(vpriv[9], sf);
      else wf[OFF_CNT + b4 * 128 + o4] = __fadd_rn(wf[OFF_CNT + b4 * 128 + o4], sf);
      __syncthreads();  // protect WsB scratch before next phase's gemm
    }
    return;
  }

  const int dt = (g == 1) ? 1 : (g == 2) ? 2 : (g == 3) ? 3 : 4;
  const int t = p - dt;
  if (t < 0 || t >= NT) return;

  const unsigned char* Ab; const float* Wm;
  switch (g) {
    case 1:  Ab = sb + BS0 + (size_t)prev * 131072; Wm = W1;  break;
    case 2:  Ab = sb + BS1 + (size_t)prev * 131072; Wm = W2a; break;
    case 3:  Ab = sb + BS2 + (size_t)prev * 131072; Wm = W2b; break;
    default: Ab = sb + BS2 + (size_t)prev * 131072; Wm = W3;  break;
  }
  const int ntO = (g == 4) ? 16 : 32;
  const int N   = (g == 4) ? 512 : 1024;
  const int bBase = (lb / ntO) << 5;
  const int oBase = (lb % ntO) << 5;
  const int grp = tid >> 7, lt = tid & 127;

  float acc[4][2] = {{0.f,0.f},{0.f,0.f},{0.f,0.f},{0.f,0.f}};
  gemm_split32(Ab, Wm, bBase, oBase, grp, lt,
               AsB + grp * 2048, WsB + grp * 2304, acc);

  // fold panels (BLAS order: result = fadd(panLow, panHigh))
  float* foldp = AsB + 2048;  // group-1 As region, reads all done
  if (grp == 1) {
    float4 h0, h1;
    h0.x = acc[0][0]; h0.y = acc[0][1]; h0.z = acc[1][0]; h0.w = acc[1][1];
    h1.x = acc[2][0]; h1.y = acc[2][1]; h1.z = acc[3][0]; h1.w = acc[3][1];
    *(float4*)(foldp + lt * 8) = h0;
    *(float4*)(foldp + lt * 8 + 4) = h1;
  }
  __syncthreads();
  if (grp == 0) {
    float4 h0 = *(const float4*)(foldp + lt * 8);
    float4 h1 = *(const float4*)(foldp + lt * 8 + 4);
    acc[0][0] = __fadd_rn(acc[0][0], h0.x); acc[0][1] = __fadd_rn(acc[0][1], h0.y);
    acc[1][0] = __fadd_rn(acc[1][0], h0.z); acc[1][1] = __fadd_rn(acc[1][1], h0.w);
    acc[2][0] = __fadd_rn(acc[2][0], h1.x); acc[2][1] = __fadd_rn(acc[2][1], h1.y);
    acc[3][0] = __fadd_rn(acc[3][0], h1.z); acc[3][1] = __fadd_rn(acc[3][1], h1.w);

    const int tb4 = (lt >> 4) << 2, to2 = (lt & 15) << 1;
    if (g == 2) {
      float* dst = c2a + (size_t)cur * 131072;
#pragma unroll
      for (int i = 0; i < 4; ++i) {
        const int b = bBase + tb4 + i;
        F2U u; u.f.x = acc[i][0]; u.f.y = acc[i][1];
        st_u64_agent(dst + (size_t)b * 1024 + oBase + to2, u.u);
      }
    } else {
      float alpha; float* vg; unsigned char* sOut;
      if (g == 1)      { alpha = 0.95f; vg = wf + OFF_V1; sOut = sb + BS1 + (size_t)cur * 131072; }
      else if (g == 3) { alpha = 0.93f; vg = wf + OFF_V2; sOut = sb + BS2 + (size_t)cur * 131072; }
      else             { alpha = 0.90f; vg = wf + OFF_V3; sOut = sb + BS3 + (size_t)cur * 65536;  }
      const float* c2aPrev = c2a + (size_t)prev * 131072;
#pragma unroll
      for (int i = 0; i < 4; ++i) {
        const int b = bBase + tb4 + i;
        float cin[2];
        if (g == 3) {
          F2U u; u.u = ld_u64_agentf(c2aPrev + (size_t)b * 1024 + oBase + to2);
          // reference: ONE __fadd_rn combining the two matmuls, W2a first
          cin[0] = __fadd_rn(u.f.x, acc[i][0]);
          cin[1] = __fadd_rn(u.f.y, acc[i][1]);
        } else {
          cin[0] = acc[i][0]; cin[1] = acc[i][1];
        }
        int si[2];
#pragma unroll
        for (int j = 0; j < 2; ++j) {
          const int o = oBase + to2 + j;
          float vold = PERSIST ? vpriv[i*2+j] : vg[(size_t)b * N + o];
          float vv = __fadd_rn(__fmul_rn(alpha, vold), cin[j]);
          int s = (vv >= 0.5f) ? 1 : 0;
          float sf = (float)s;
          float nv = __fmul_rn(vv, __fsub_rn(1.0f, sf));
          if (PERSIST) vpriv[i*2+j] = nv; else vg[(size_t)b * N + o] = nv;
          si[j] = s;
        }
        st_u16_agent(sOut + (size_t)b * N + oBase + to2,
                     (unsigned short)(si[0] | (si[1] << 8)));
      }
    }
  }
}

__device__ __forceinline__ void df_wait(const unsigned* C, unsigned tgt) {
  while (ld_u32_agent(C) < tgt) __builtin_amdgcn_s_sleep(2);
}

__global__ __launch_bounds__(256) void pre_kernel(float* __restrict__ wf) {
  size_t i = (size_t)blockIdx.x * blockDim.x + threadIdx.x;
  size_t stride = (size_t)gridDim.x * blockDim.x;
  for (size_t j = i; j < WS_TOTAL; j += stride) wf[j] = 0.0f;
}

// ---- persistent dataflow kernel ----
__global__ __launch_bounds__(256, 2) void persist4(
    const float* __restrict__ x,
    const float* __restrict__ W0, const float* __restrict__ W1,
    const float* __restrict__ W2a, const float* __restrict__ W2b,
    const float* __restrict__ W3, const float* __restrict__ W4,
    float* __restrict__ wf, float* __restrict__ out)
{
  __shared__ float AsB[4096];       // 16 KB (2 groups x 2 buf x 1024)
  __shared__ float WsB[4608];       // 18.4 KB (also L4 staging scratch)
  __shared__ float vLds[256][11];   // 11.3 KB per-thread v/cnt state
  const int tid = threadIdx.x;
  float* vpriv = &vLds[tid][0];
#pragma unroll
  for (int i = 0; i < 11; ++i) vpriv[i] = 0.0f;

  unsigned* C = (unsigned*)(wf + OFF_ARR);  // C[g] at C + 16*g

  const int blk = blockIdx.x;
  int g, lb;
  if (blk < 64)       { g = 0; lb = blk; }
  else if (blk < 192) { g = 1; lb = blk - 64; }
  else if (blk < 320) { g = 2; lb = blk - 192; }
  else if (blk < 448) { g = 3; lb = blk - 320; }
  else                { g = 4; lb = blk - 448; }

  for (int p = 0; p < NT + 5; ++p) {
    if (tid == 0) {
      const unsigned p128 = (unsigned)p * 128u, p64 = (unsigned)p * 64u;
      switch (g) {
        case 0: df_wait(C + 16, p128); df_wait(C + 64, p64);  break;
        case 1: df_wait(C + 0,  p64);  df_wait(C + 32, p128); break;
        case 2: df_wait(C + 16, p128); df_wait(C + 48, p128); break;
        case 3: df_wait(C + 32, p128); df_wait(C + 48, p128);
                df_wait(C + 64, p64);  break;
        default: df_wait(C + 48, p128); df_wait(C + 0, p64);  break;
      }
    }
    __syncthreads();
    do_phase512<true>(g, lb, p, x, W0, W1, W2a, W2b, W3, W4, wf, out,
                      AsB, WsB, vpriv);
    __syncthreads();  // drains all waves' vmem (sc1 stores now at IF)
    if (tid == 0)
      __hip_atomic_fetch_add(C + 16 * g, 1u, __ATOMIC_RELAXED,
                             __HIP_MEMORY_SCOPE_AGENT);
  }

  if (g == 0) {  // counts epilogue (plain stores, flushed at kernel end)
    const int b4 = ((lb >> 4) << 5) + (tid >> 3);
    const int o4 = ((lb & 15) << 3) + (tid & 7);
    out[(size_t)128 * NT * 128 + (size_t)b4 * 128 + o4] = vpriv[9];
  }
}

// ---------------------------------------------------------------------------
// ------------------------ FALLBACK: multi-launch ---------------------------
// ---------------------------------------------------------------------------

__global__ __launch_bounds__(256) void init_kernel(float* __restrict__ wf) {
  size_t i = (size_t)blockIdx.x * blockDim.x + threadIdx.x;
  size_t stride = (size_t)gridDim.x * blockDim.x;
  for (size_t j = i; j < WS_TOTAL; j += stride) wf[j] = 0.0f;
}

__global__ __launch_bounds__(256) void phase_kernel512(
    const float* __restrict__ x,
    const float* __restrict__ W0, const float* __restrict__ W1,
    const float* __restrict__ W2a, const float* __restrict__ W2b,
    const float* __restrict__ W3, const float* __restrict__ W4,
    float* __restrict__ wf, float* __restrict__ out, int p)
{
  __shared__ float AsB[4096];
  __shared__ float WsB[4608];
  const int blk = blockIdx.x;
  int g, lb;
  if (blk < 64)       { g = 0; lb = blk; }
  else if (blk < 192) { g = 1; lb = blk - 64; }
  else if (blk < 320) { g = 2; lb = blk - 192; }
  else if (blk < 448) { g = 3; lb = blk - 320; }
  else                { g = 4; lb = blk - 448; }
  float vd[11];
  do_phase512<false>(g, lb, p, x, W0, W1, W2a, W2b, W3, W4, wf, out,
                     AsB, WsB, vd);
}

__global__ __launch_bounds__(256) void fin_kernel(const float* __restrict__ counts,
                                                  float* __restrict__ out) {
  int i = blockIdx.x * blockDim.x + threadIdx.x;
  if (i < 128 * 128) out[(size_t)128 * NT * 128 + i] = counts[i];
}

// ---------------------------------------------------------------------------
// -------------------------------- launcher ---------------------------------
// ---------------------------------------------------------------------------

extern "C" void kernel_launch(void* const* d_in, const int* in_sizes, int n_in,
                              void* d_out, int out_size, void* d_ws, size_t ws_size,
                              hipStream_t stream) {
  const float* x   = (const float*)d_in[0];
  const float* W0  = (const float*)d_in[1];
  const float* W1  = (const float*)d_in[2];
  const float* W2a = (const float*)d_in[3];
  const float* W2b = (const float*)d_in[4];
  const float* W3  = (const float*)d_in[5];
  const float* W4  = (const float*)d_in[6];
  float* wf  = (float*)d_ws;
  float* out = (float*)d_out;

  int maxBlocksPerCU = 0;
  hipError_t qe = hipOccupancyMaxActiveBlocksPerMultiprocessor(
      &maxBlocksPerCU, persist4, 256, 0);
  const bool wsOK = ws_size >= WS_TOTAL * sizeof(float);

  if (qe == hipSuccess && maxBlocksPerCU >= 2 && wsOK) {
    pre_kernel<<<256, 256, 0, stream>>>(wf);
    persist4<<<NBLK, 256, 0, stream>>>(x, W0, W1, W2a, W2b, W3, W4, wf, out);
  } else {
    (void)hipGetLastError();
    init_kernel<<<512, 256, 0, stream>>>(wf);
    for (int p = 0; p < NT + 5; ++p) {
      phase_kernel512<<<NBLK, 256, 0, stream>>>(x, W0, W1, W2a, W2b, W3, W4,
                                                wf, out, p);
    }
    fin_kernel<<<64, 256, 0, stream>>>(wf + OFF_CNT, out);
  }
}